// Round 1
// baseline (2084.232 us; speedup 1.0000x reference)
//
#include <hip/hip_runtime.h>

#define NN 100000
#define NE 800000
#define DD 128
#define NL 4
#define NG 512
#define NT 10
#define BN_EPS 1e-5f

__device__ __forceinline__ float atomAddF(float* p, float v) {
  return unsafeAtomicAdd(p, v);
}

// ---------------- kernels ----------------

__global__ __launch_bounds__(256) void atom_encoder_kernel(
    const int* __restrict__ x, const float* __restrict__ atom_emb,
    float* __restrict__ h) {
  int idx = blockIdx.x * 256 + threadIdx.x;
  int n = idx >> 7, d = idx & 127;
  if (n >= NN) return;
  const int* xr = x + n * 9;
  float acc = 0.f;
#pragma unroll
  for (int f = 0; f < 9; ++f) {
    acc += atom_emb[(f * 64 + xr[f]) * DD + d];
  }
  h[idx] = acc;
}

__global__ __launch_bounds__(256) void deg_count_kernel(
    const int* __restrict__ ei, int* __restrict__ degcnt) {
  int e = blockIdx.x * 256 + threadIdx.x;
  if (e < NE) atomicAdd(&degcnt[ei[e]], 1);
}

__global__ __launch_bounds__(256) void deg_fin_kernel(
    const int* __restrict__ degcnt, float* __restrict__ deg,
    float* __restrict__ dinv) {
  int n = blockIdx.x * 256 + threadIdx.x;
  if (n < NN) {
    float dv = (float)degcnt[n] + 1.f;
    deg[n] = dv;
    dinv[n] = rsqrtf(dv);
  }
}

__global__ __launch_bounds__(256) void norm_kernel(
    const int* __restrict__ ei, const float* __restrict__ dinv,
    float* __restrict__ norm) {
  int e = blockIdx.x * 256 + threadIdx.x;
  if (e < NE) norm[e] = dinv[ei[e]] * dinv[ei[NE + e]];
}

__global__ __launch_bounds__(256) void gcount_kernel(
    const int* __restrict__ batch, int* __restrict__ gcount) {
  int n = blockIdx.x * 256 + threadIdx.x;
  if (n < NN) atomicAdd(&gcount[batch[n]], 1);
}

// C[n,:] = act(A[n,:]) @ W + bias, where act is optional fused BN+ReLU
__global__ __launch_bounds__(256) void gemm_bias_kernel(
    const float* __restrict__ A, const float* __restrict__ W,
    const float* __restrict__ bias, const float* __restrict__ bn_scale,
    const float* __restrict__ bn_shift, int fuse_bn, float* __restrict__ C) {
  __shared__ float Ws[DD * DD];
  __shared__ float As[16 * 64];
  __shared__ float sc_s[DD], sh_s[DD];
  for (int i = threadIdx.x; i < DD * DD; i += 256) Ws[i] = W[i];
  if (threadIdx.x < DD) {
    sc_s[threadIdx.x] = fuse_bn ? bn_scale[threadIdx.x] : 1.f;
    sh_s[threadIdx.x] = fuse_bn ? bn_shift[threadIdx.x] : 0.f;
  }
  const int row0 = blockIdx.x * 64;
  const int tx = threadIdx.x & 31, ty = threadIdx.x >> 5;
  const int lr = threadIdx.x >> 2, lc = (threadIdx.x & 3) * 4;
  float acc[8][4] = {};
  __syncthreads();
  for (int k0 = 0; k0 < DD; k0 += 16) {
    float4 a4 = make_float4(0.f, 0.f, 0.f, 0.f);
    int grow = row0 + lr;
    if (grow < NN) a4 = *reinterpret_cast<const float4*>(&A[grow * DD + k0 + lc]);
    if (fuse_bn) {
      a4.x = fmaxf(a4.x * sc_s[k0 + lc + 0] + sh_s[k0 + lc + 0], 0.f);
      a4.y = fmaxf(a4.y * sc_s[k0 + lc + 1] + sh_s[k0 + lc + 1], 0.f);
      a4.z = fmaxf(a4.z * sc_s[k0 + lc + 2] + sh_s[k0 + lc + 2], 0.f);
      a4.w = fmaxf(a4.w * sc_s[k0 + lc + 3] + sh_s[k0 + lc + 3], 0.f);
    }
    // transpose-stage: As[k][r]
    As[(lc + 0) * 64 + lr] = a4.x;
    As[(lc + 1) * 64 + lr] = a4.y;
    As[(lc + 2) * 64 + lr] = a4.z;
    As[(lc + 3) * 64 + lr] = a4.w;
    __syncthreads();
#pragma unroll
    for (int kk = 0; kk < 16; ++kk) {
      float4 w4 = *reinterpret_cast<const float4*>(&Ws[(k0 + kk) * DD + tx * 4]);
      float a[8];
#pragma unroll
      for (int i = 0; i < 8; ++i) a[i] = As[kk * 64 + ty * 8 + i];
#pragma unroll
      for (int i = 0; i < 8; ++i) {
        acc[i][0] = fmaf(a[i], w4.x, acc[i][0]);
        acc[i][1] = fmaf(a[i], w4.y, acc[i][1]);
        acc[i][2] = fmaf(a[i], w4.z, acc[i][2]);
        acc[i][3] = fmaf(a[i], w4.w, acc[i][3]);
      }
    }
    __syncthreads();
  }
  float4 b4 = *reinterpret_cast<const float4*>(&bias[tx * 4]);
#pragma unroll
  for (int i = 0; i < 8; ++i) {
    int grow = row0 + ty * 8 + i;
    if (grow < NN) {
      float4 o;
      o.x = acc[i][0] + b4.x;
      o.y = acc[i][1] + b4.y;
      o.z = acc[i][2] + b4.z;
      o.w = acc[i][3] + b4.w;
      *reinterpret_cast<float4*>(&C[grow * DD + tx * 4]) = o;
    }
  }
}

__global__ __launch_bounds__(256) void edge_scatter_kernel(
    const int* __restrict__ ei, const int* __restrict__ eattr,
    const float* __restrict__ norm, const float* __restrict__ hl,
    const float* __restrict__ bemb, float* __restrict__ aggr) {
  int idx = blockIdx.x * 256 + threadIdx.x;
  int e = idx >> 7;
  if (e >= NE) return;
  int d = idx & 127;
  int r = ei[e], c = ei[NE + e];
  float nm = norm[e];
  int a0 = eattr[e * 3 + 0], a1 = eattr[e * 3 + 1], a2 = eattr[e * 3 + 2];
  float bv = bemb[(0 * 8 + a0) * DD + d] + bemb[(1 * 8 + a1) * DD + d] +
             bemb[(2 * 8 + a2) * DD + d];
  float msg = nm * fmaxf(hl[r * DD + d] + bv, 0.f);
  atomAddF(&aggr[c * DD + d], msg);
}

__global__ __launch_bounds__(256) void update_kernel(
    float* __restrict__ h, const float* __restrict__ hl,
    const float* __restrict__ root, const float* __restrict__ deg,
    float* __restrict__ bn_sum, float* __restrict__ bn_sq, int do_stats) {
  int d = threadIdx.x & 127;
  int rslot = threadIdx.x >> 7;
  float ls = 0.f, lsq = 0.f;
  float rt = root[d];
  for (int n = blockIdx.x * 2 + rslot; n < NN; n += gridDim.x * 2) {
    float v = h[n * DD + d] + fmaxf(hl[n * DD + d] + rt, 0.f) / deg[n];
    h[n * DD + d] = v;
    ls += v;
    lsq += v * v;
  }
  if (do_stats) {
    __shared__ float s0[DD], s1[DD];
    if (rslot == 0) {
      s0[d] = ls;
      s1[d] = lsq;
    }
    __syncthreads();
    if (rslot == 1) {
      atomAddF(&bn_sum[d], s0[d] + ls);
      atomAddF(&bn_sq[d], s1[d] + lsq);
    }
  }
}

__global__ __launch_bounds__(128) void bn_finalize_kernel(
    const float* __restrict__ bn_sum, const float* __restrict__ bn_sq,
    const float* __restrict__ gamma, const float* __restrict__ beta,
    float* __restrict__ scale, float* __restrict__ shift) {
  int d = threadIdx.x;
  float mu = bn_sum[d] / (float)NN;
  float var = bn_sq[d] / (float)NN - mu * mu;
  float inv = rsqrtf(var + BN_EPS);
  float sc = gamma[d] * inv;
  scale[d] = sc;
  shift[d] = beta[d] - mu * sc;
}

__global__ __launch_bounds__(256) void pool_kernel(
    const float* __restrict__ h, const int* __restrict__ batch,
    float* __restrict__ hg) {
  int idx = blockIdx.x * 256 + threadIdx.x;
  int n = idx >> 7, d = idx & 127;
  if (n >= NN) return;
  atomAddF(&hg[batch[n] * DD + d], h[idx]);
}

__global__ __launch_bounds__(128) void mlp_kernel(
    const float* __restrict__ hg, const int* __restrict__ gcount,
    const float* __restrict__ W1, const float* __restrict__ b1,
    const float* __restrict__ W2, const float* __restrict__ b2,
    float* __restrict__ out) {
  int g = blockIdx.x, t = threadIdx.x;
  __shared__ float row[DD], t1[DD];
  float cnt = fmaxf((float)gcount[g], 1.f);
  row[t] = fmaxf(hg[g * DD + t] / cnt, 0.f);
  __syncthreads();
  float acc = b1[t];
  for (int k = 0; k < DD; ++k) acc = fmaf(row[k], W1[k * DD + t], acc);
  t1[t] = fmaxf(acc, 0.f);
  __syncthreads();
  if (t < NT) {
    float acc2 = b2[t];
    for (int k = 0; k < DD; ++k) acc2 = fmaf(t1[k], W2[k * NT + t], acc2);
    out[g * NT + t] = acc2;
  }
}

extern "C" void kernel_launch(void* const* d_in, const int* in_sizes, int n_in,
                              void* d_out, int out_size, void* d_ws,
                              size_t ws_size, hipStream_t stream) {
  const int* x = (const int*)d_in[0];
  const int* edge_index = (const int*)d_in[1];
  const int* batch = (const int*)d_in[2];
  const int* edge_attr = (const int*)d_in[3];
  const float* atom_emb = (const float*)d_in[4];
  const float* W = (const float*)d_in[5];
  const float* b = (const float*)d_in[6];
  const float* root = (const float*)d_in[7];
  const float* bond_emb = (const float*)d_in[8];
  const float* gamma = (const float*)d_in[9];
  const float* beta = (const float*)d_in[10];
  const float* W1 = (const float*)d_in[11];
  const float* b1 = (const float*)d_in[12];
  const float* W2 = (const float*)d_in[13];
  const float* b2 = (const float*)d_in[14];
  float* out = (float*)d_out;

  char* ws = (char*)d_ws;
  size_t off = 0;
  auto alloc = [&](size_t bytes) {
    char* p = ws + off;
    off += (bytes + 255) & ~size_t(255);
    return p;
  };
  float* h = (float*)alloc(sizeof(float) * NN * DD);
  float* hl = (float*)alloc(sizeof(float) * NN * DD);
  float* norm = (float*)alloc(sizeof(float) * NE);
  float* deg = (float*)alloc(sizeof(float) * NN);
  float* dinv = (float*)alloc(sizeof(float) * NN);
  int* degcnt = (int*)alloc(sizeof(int) * NN);
  float* bn_sum = (float*)alloc(sizeof(float) * DD);
  float* bn_sq = (float*)alloc(sizeof(float) * DD);
  float* bsc = (float*)alloc(sizeof(float) * DD);
  float* bsh = (float*)alloc(sizeof(float) * DD);
  float* hg = (float*)alloc(sizeof(float) * NG * DD);
  int* gcount = (int*)alloc(sizeof(int) * NG);

  hipMemsetAsync(degcnt, 0, sizeof(int) * NN, stream);
  hipMemsetAsync(gcount, 0, sizeof(int) * NG, stream);
  hipMemsetAsync(hg, 0, sizeof(float) * NG * DD, stream);

  atom_encoder_kernel<<<(NN * DD) / 256, 256, 0, stream>>>(x, atom_emb, h);
  deg_count_kernel<<<(NE + 255) / 256, 256, 0, stream>>>(edge_index, degcnt);
  deg_fin_kernel<<<(NN + 255) / 256, 256, 0, stream>>>(degcnt, deg, dinv);
  norm_kernel<<<(NE + 255) / 256, 256, 0, stream>>>(edge_index, dinv, norm);
  gcount_kernel<<<(NN + 255) / 256, 256, 0, stream>>>(batch, gcount);

  for (int l = 0; l < NL; ++l) {
    gemm_bias_kernel<<<(NN + 63) / 64, 256, 0, stream>>>(
        h, W + l * DD * DD, b + l * DD, bsc, bsh, l > 0 ? 1 : 0, hl);
    hipMemsetAsync(h, 0, sizeof(float) * NN * DD, stream);
    edge_scatter_kernel<<<(NE * DD) / 256, 256, 0, stream>>>(
        edge_index, edge_attr, norm, hl, bond_emb + l * 3 * 8 * DD, h);
    int do_stats = (l < NL - 1) ? 1 : 0;
    if (do_stats) {
      hipMemsetAsync(bn_sum, 0, sizeof(float) * DD, stream);
      hipMemsetAsync(bn_sq, 0, sizeof(float) * DD, stream);
    }
    update_kernel<<<1024, 256, 0, stream>>>(h, hl, root + l * DD, deg, bn_sum,
                                            bn_sq, do_stats);
    if (do_stats) {
      bn_finalize_kernel<<<1, DD, 0, stream>>>(bn_sum, bn_sq, gamma + l * DD,
                                               beta + l * DD, bsc, bsh);
    }
  }

  pool_kernel<<<(NN * DD) / 256, 256, 0, stream>>>(h, batch, hg);
  mlp_kernel<<<NG, DD, 0, stream>>>(hg, gcount, W1, b1, W2, b2, out);
}

// Round 2
// 1072.088 us; speedup vs baseline: 1.9441x; 1.9441x over previous
//
#include <hip/hip_runtime.h>

#define NN 100000
#define NE 800000
#define DD 128
#define NL 4
#define NG 512
#define NT 10
#define BN_EPS 1e-5f
#define SCAN_B 1024

__device__ __forceinline__ float atomAddF(float* p, float v) {
  return unsafeAtomicAdd(p, v);
}

// ---------------- setup kernels ----------------

__global__ __launch_bounds__(256) void atom_encoder_kernel(
    const int* __restrict__ x, const float* __restrict__ atom_emb,
    float* __restrict__ h) {
  int idx = blockIdx.x * 256 + threadIdx.x;
  int n = idx >> 7, d = idx & 127;
  if (n >= NN) return;
  const int* xr = x + n * 9;
  float acc = 0.f;
#pragma unroll
  for (int f = 0; f < 9; ++f) acc += atom_emb[(f * 64 + xr[f]) * DD + d];
  h[idx] = acc;
}

__global__ __launch_bounds__(256) void count_kernel(
    const int* __restrict__ idxs, int* __restrict__ cnt, int n) {
  int e = blockIdx.x * 256 + threadIdx.x;
  if (e < n) atomicAdd(&cnt[idxs[e]], 1);
}

__global__ __launch_bounds__(256) void deg_fin_kernel(
    const int* __restrict__ degcnt, float* __restrict__ degrecip,
    float* __restrict__ dinv) {
  int n = blockIdx.x * 256 + threadIdx.x;
  if (n < NN) {
    float dv = (float)degcnt[n] + 1.f;
    degrecip[n] = 1.f / dv;
    dinv[n] = rsqrtf(dv);
  }
}

__global__ __launch_bounds__(256) void norm_kernel(
    const int* __restrict__ ei, const float* __restrict__ dinv,
    float* __restrict__ norm) {
  int e = blockIdx.x * 256 + threadIdx.x;
  if (e < NE) norm[e] = dinv[ei[e]] * dinv[ei[NE + e]];
}

// ---------------- CSR build ----------------

__global__ __launch_bounds__(256) void scan1_kernel(
    const int* __restrict__ in, int* __restrict__ out, int* __restrict__ bsum,
    int n) {
  __shared__ int s[256];
  int base = blockIdx.x * SCAN_B + threadIdx.x * 4;
  int v[4] = {0, 0, 0, 0};
  if (base + 3 < n) {
    int4 t = *reinterpret_cast<const int4*>(&in[base]);
    v[0] = t.x; v[1] = t.y; v[2] = t.z; v[3] = t.w;
  } else {
    for (int i = 0; i < 4; ++i) v[i] = (base + i < n) ? in[base + i] : 0;
  }
  int tsum = v[0] + v[1] + v[2] + v[3];
  s[threadIdx.x] = tsum;
  __syncthreads();
  for (int d = 1; d < 256; d <<= 1) {
    int t = (threadIdx.x >= d) ? s[threadIdx.x - d] : 0;
    __syncthreads();
    s[threadIdx.x] += t;
    __syncthreads();
  }
  int run = s[threadIdx.x] - tsum;
  if (threadIdx.x == 255) bsum[blockIdx.x] = s[255];
  for (int i = 0; i < 4; ++i) {
    if (base + i < n) out[base + i] = run;
    run += v[i];
  }
}

__global__ void scan2_kernel(int* bsum, int nb) {
  __shared__ int s[128];
  int v = (threadIdx.x < nb) ? bsum[threadIdx.x] : 0;
  s[threadIdx.x] = v;
  __syncthreads();
  for (int d = 1; d < 128; d <<= 1) {
    int t = (threadIdx.x >= d) ? s[threadIdx.x - d] : 0;
    __syncthreads();
    s[threadIdx.x] += t;
    __syncthreads();
  }
  if (threadIdx.x < nb) bsum[threadIdx.x] = s[threadIdx.x] - v;
}

__global__ __launch_bounds__(256) void scan3_kernel(int* off, const int* bsum,
                                                    int n, int total) {
  int i = blockIdx.x * 256 + threadIdx.x;
  if (i < n) off[i] += bsum[i / SCAN_B];
  if (i == 0) off[n] = total;
}

__global__ __launch_bounds__(256) void csr_fill_kernel(
    const int* __restrict__ ei, const int* __restrict__ eattr,
    const float* __restrict__ norm, const int* __restrict__ off,
    int* __restrict__ cursor, int4* __restrict__ edata) {
  int e = blockIdx.x * 256 + threadIdx.x;
  if (e >= NE) return;
  int c = ei[NE + e];
  int pos = atomicAdd(&cursor[c], 1);
  int4 d;
  d.x = ei[e];
  d.y = __float_as_int(norm[e]);
  d.z = eattr[e * 3] | (eattr[e * 3 + 1] << 8) | (eattr[e * 3 + 2] << 16);
  d.w = 0;
  edata[off[c] + pos] = d;
}

__global__ void gscan_kernel(const int* __restrict__ gcount,
                             int* __restrict__ gstart) {
  __shared__ int s[NG];
  int v = gcount[threadIdx.x];
  s[threadIdx.x] = v;
  __syncthreads();
  for (int d = 1; d < NG; d <<= 1) {
    int t = (threadIdx.x >= d) ? s[threadIdx.x - d] : 0;
    __syncthreads();
    s[threadIdx.x] += t;
    __syncthreads();
  }
  gstart[threadIdx.x] = s[threadIdx.x] - v;
  if (threadIdx.x == NG - 1) gstart[NG] = s[NG - 1];
}

// ---------------- GEMM: C = act(A) @ W + bias ----------------

__global__ __launch_bounds__(256) void gemm_bias_kernel(
    const float* __restrict__ A, const float* __restrict__ W,
    const float* __restrict__ bias, const float* __restrict__ bn_scale,
    const float* __restrict__ bn_shift, int fuse_bn, float* __restrict__ C) {
  __shared__ float Ws[DD * DD];
  __shared__ float As[16 * 64];
  __shared__ float sc_s[DD], sh_s[DD];
  for (int i = threadIdx.x; i < DD * DD; i += 256) Ws[i] = W[i];
  if (threadIdx.x < DD) {
    sc_s[threadIdx.x] = fuse_bn ? bn_scale[threadIdx.x] : 1.f;
    sh_s[threadIdx.x] = fuse_bn ? bn_shift[threadIdx.x] : 0.f;
  }
  const int row0 = blockIdx.x * 64;
  const int tx = threadIdx.x & 31, ty = threadIdx.x >> 5;
  const int lr = threadIdx.x >> 2, lc = (threadIdx.x & 3) * 4;
  float acc[8][4] = {};
  __syncthreads();
  for (int k0 = 0; k0 < DD; k0 += 16) {
    float4 a4 = make_float4(0.f, 0.f, 0.f, 0.f);
    int grow = row0 + lr;
    if (grow < NN) a4 = *reinterpret_cast<const float4*>(&A[grow * DD + k0 + lc]);
    if (fuse_bn) {
      a4.x = fmaxf(a4.x * sc_s[k0 + lc + 0] + sh_s[k0 + lc + 0], 0.f);
      a4.y = fmaxf(a4.y * sc_s[k0 + lc + 1] + sh_s[k0 + lc + 1], 0.f);
      a4.z = fmaxf(a4.z * sc_s[k0 + lc + 2] + sh_s[k0 + lc + 2], 0.f);
      a4.w = fmaxf(a4.w * sc_s[k0 + lc + 3] + sh_s[k0 + lc + 3], 0.f);
    }
    As[(lc + 0) * 64 + lr] = a4.x;
    As[(lc + 1) * 64 + lr] = a4.y;
    As[(lc + 2) * 64 + lr] = a4.z;
    As[(lc + 3) * 64 + lr] = a4.w;
    __syncthreads();
#pragma unroll
    for (int kk = 0; kk < 16; ++kk) {
      float4 w4 = *reinterpret_cast<const float4*>(&Ws[(k0 + kk) * DD + tx * 4]);
      float a[8];
#pragma unroll
      for (int i = 0; i < 8; ++i) a[i] = As[kk * 64 + ty * 8 + i];
#pragma unroll
      for (int i = 0; i < 8; ++i) {
        acc[i][0] = fmaf(a[i], w4.x, acc[i][0]);
        acc[i][1] = fmaf(a[i], w4.y, acc[i][1]);
        acc[i][2] = fmaf(a[i], w4.z, acc[i][2]);
        acc[i][3] = fmaf(a[i], w4.w, acc[i][3]);
      }
    }
    __syncthreads();
  }
  float4 b4 = *reinterpret_cast<const float4*>(&bias[tx * 4]);
#pragma unroll
  for (int i = 0; i < 8; ++i) {
    int grow = row0 + ty * 8 + i;
    if (grow < NN) {
      float4 o;
      o.x = acc[i][0] + b4.x;
      o.y = acc[i][1] + b4.y;
      o.z = acc[i][2] + b4.z;
      o.w = acc[i][3] + b4.w;
      *reinterpret_cast<float4*>(&C[grow * DD + tx * 4]) = o;
    }
  }
}

// ---------------- fused gather + update + BN stats ----------------
// one wave per destination node; lanes own channels {lane, lane+64}

__global__ __launch_bounds__(256) void gather_update_kernel(
    const int* __restrict__ off, const int4* __restrict__ edata,
    const float* __restrict__ hl, const float* __restrict__ bemb,
    const float* __restrict__ root, const float* __restrict__ degrecip,
    float* __restrict__ h, float* __restrict__ bn_sum,
    float* __restrict__ bn_sq, int do_stats) {
  __shared__ float bembS[24 * DD];
  for (int i = threadIdx.x; i < 24 * DD; i += 256) bembS[i] = bemb[i];
  int wid = threadIdx.x >> 6;
  int lane = threadIdx.x & 63;
  int d0 = lane, d1 = lane + 64;
  float rt0 = root[d0], rt1 = root[d1];
  float ls0 = 0, ls1 = 0, lq0 = 0, lq1 = 0;
  __syncthreads();
  for (int n = blockIdx.x * 4 + wid; n < NN; n += gridDim.x * 4) {
    int k0 = off[n], k1 = off[n + 1];
    float acc0 = 0.f, acc1 = 0.f;
    for (int k = k0; k < k1; ++k) {
      int4 ed = edata[k];
      int r = ed.x;
      float nm = __int_as_float(ed.y);
      int a0 = ed.z & 255, a1 = (ed.z >> 8) & 255, a2 = (ed.z >> 16) & 255;
      float b00 = bembS[a0 * DD + d0] + bembS[(8 + a1) * DD + d0] +
                  bembS[(16 + a2) * DD + d0];
      float b01 = bembS[a0 * DD + d1] + bembS[(8 + a1) * DD + d1] +
                  bembS[(16 + a2) * DD + d1];
      acc0 += nm * fmaxf(hl[r * DD + d0] + b00, 0.f);
      acc1 += nm * fmaxf(hl[r * DD + d1] + b01, 0.f);
    }
    float dr = degrecip[n];
    float v0 = acc0 + fmaxf(hl[n * DD + d0] + rt0, 0.f) * dr;
    float v1 = acc1 + fmaxf(hl[n * DD + d1] + rt1, 0.f) * dr;
    h[n * DD + d0] = v0;
    h[n * DD + d1] = v1;
    ls0 += v0; ls1 += v1;
    lq0 += v0 * v0; lq1 += v1 * v1;
  }
  if (do_stats) {
    __shared__ float s0[DD], s1[DD];
    if (wid == 0) {
      s0[d0] = ls0; s0[d1] = ls1;
      s1[d0] = lq0; s1[d1] = lq1;
    }
    __syncthreads();
#pragma unroll
    for (int w = 1; w < 4; ++w) {
      if (wid == w) {
        s0[d0] += ls0; s0[d1] += ls1;
        s1[d0] += lq0; s1[d1] += lq1;
      }
      __syncthreads();
    }
    if (threadIdx.x < DD) {
      atomAddF(&bn_sum[threadIdx.x], s0[threadIdx.x]);
      atomAddF(&bn_sq[threadIdx.x], s1[threadIdx.x]);
    }
  }
}

__global__ __launch_bounds__(128) void bn_finalize_kernel(
    const float* __restrict__ bn_sum, const float* __restrict__ bn_sq,
    const float* __restrict__ gamma, const float* __restrict__ beta,
    float* __restrict__ scale, float* __restrict__ shift) {
  int d = threadIdx.x;
  float mu = bn_sum[d] / (float)NN;
  float var = bn_sq[d] / (float)NN - mu * mu;
  float inv = rsqrtf(var + BN_EPS);
  float sc = gamma[d] * inv;
  scale[d] = sc;
  shift[d] = beta[d] - mu * sc;
}

// ---------------- pool (sorted batch, segmented) + MLP ----------------

__global__ __launch_bounds__(128) void pool_mlp_kernel(
    const float* __restrict__ h, const int* __restrict__ gstart,
    const float* __restrict__ W1, const float* __restrict__ b1,
    const float* __restrict__ W2, const float* __restrict__ b2,
    float* __restrict__ out) {
  int g = blockIdx.x, t = threadIdx.x;
  int s = gstart[g], e = gstart[g + 1];
  float acc = 0.f;
  for (int n = s; n < e; ++n) acc += h[n * DD + t];
  float cnt = fmaxf((float)(e - s), 1.f);
  __shared__ float row[DD], t1[DD];
  row[t] = fmaxf(acc / cnt, 0.f);
  __syncthreads();
  float a1v = b1[t];
  for (int k = 0; k < DD; ++k) a1v = fmaf(row[k], W1[k * DD + t], a1v);
  t1[t] = fmaxf(a1v, 0.f);
  __syncthreads();
  if (t < NT) {
    float a2 = b2[t];
    for (int k = 0; k < DD; ++k) a2 = fmaf(t1[k], W2[k * NT + t], a2);
    out[g * NT + t] = a2;
  }
}

extern "C" void kernel_launch(void* const* d_in, const int* in_sizes, int n_in,
                              void* d_out, int out_size, void* d_ws,
                              size_t ws_size, hipStream_t stream) {
  const int* x = (const int*)d_in[0];
  const int* edge_index = (const int*)d_in[1];
  const int* batch = (const int*)d_in[2];
  const int* edge_attr = (const int*)d_in[3];
  const float* atom_emb = (const float*)d_in[4];
  const float* W = (const float*)d_in[5];
  const float* b = (const float*)d_in[6];
  const float* root = (const float*)d_in[7];
  const float* bond_emb = (const float*)d_in[8];
  const float* gamma = (const float*)d_in[9];
  const float* beta = (const float*)d_in[10];
  const float* W1 = (const float*)d_in[11];
  const float* b1 = (const float*)d_in[12];
  const float* W2 = (const float*)d_in[13];
  const float* b2 = (const float*)d_in[14];
  float* out = (float*)d_out;

  char* ws = (char*)d_ws;
  size_t off_b = 0;
  auto alloc = [&](size_t bytes) {
    char* p = ws + off_b;
    off_b += (bytes + 255) & ~size_t(255);
    return p;
  };
  float* h = (float*)alloc(sizeof(float) * NN * DD);
  float* hl = (float*)alloc(sizeof(float) * NN * DD);
  float* norm = (float*)alloc(sizeof(float) * NE);
  int4* edata = (int4*)alloc(sizeof(int4) * NE);
  float* degrecip = (float*)alloc(sizeof(float) * NN);
  float* dinv = (float*)alloc(sizeof(float) * NN);
  int* degcnt = (int*)alloc(sizeof(int) * NN);
  int* incnt = (int*)alloc(sizeof(int) * NN);
  int* off = (int*)alloc(sizeof(int) * (NN + 1));
  int* cursor = (int*)alloc(sizeof(int) * NN);
  int* bsum = (int*)alloc(sizeof(int) * 128);
  float* bn_sum = (float*)alloc(sizeof(float) * DD);
  float* bn_sq = (float*)alloc(sizeof(float) * DD);
  float* bsc = (float*)alloc(sizeof(float) * DD);
  float* bsh = (float*)alloc(sizeof(float) * DD);
  int* gcount = (int*)alloc(sizeof(int) * NG);
  int* gstart = (int*)alloc(sizeof(int) * (NG + 1));

  hipMemsetAsync(degcnt, 0, sizeof(int) * NN, stream);
  hipMemsetAsync(incnt, 0, sizeof(int) * NN, stream);
  hipMemsetAsync(cursor, 0, sizeof(int) * NN, stream);
  hipMemsetAsync(gcount, 0, sizeof(int) * NG, stream);

  atom_encoder_kernel<<<(NN * DD) / 256, 256, 0, stream>>>(x, atom_emb, h);
  count_kernel<<<(NE + 255) / 256, 256, 0, stream>>>(edge_index, degcnt, NE);
  count_kernel<<<(NE + 255) / 256, 256, 0, stream>>>(edge_index + NE, incnt, NE);
  count_kernel<<<(NN + 255) / 256, 256, 0, stream>>>(batch, gcount, NN);
  deg_fin_kernel<<<(NN + 255) / 256, 256, 0, stream>>>(degcnt, degrecip, dinv);
  norm_kernel<<<(NE + 255) / 256, 256, 0, stream>>>(edge_index, dinv, norm);

  const int nb = (NN + SCAN_B - 1) / SCAN_B;  // 98
  scan1_kernel<<<nb, 256, 0, stream>>>(incnt, off, bsum, NN);
  scan2_kernel<<<1, 128, 0, stream>>>(bsum, nb);
  scan3_kernel<<<(NN + 255) / 256, 256, 0, stream>>>(off, bsum, NN, NE);
  csr_fill_kernel<<<(NE + 255) / 256, 256, 0, stream>>>(edge_index, edge_attr,
                                                        norm, off, cursor, edata);
  gscan_kernel<<<1, NG, 0, stream>>>(gcount, gstart);

  for (int l = 0; l < NL; ++l) {
    gemm_bias_kernel<<<(NN + 63) / 64, 256, 0, stream>>>(
        h, W + l * DD * DD, b + l * DD, bsc, bsh, l > 0 ? 1 : 0, hl);
    int do_stats = (l < NL - 1) ? 1 : 0;
    if (do_stats) {
      hipMemsetAsync(bn_sum, 0, sizeof(float) * DD, stream);
      hipMemsetAsync(bn_sq, 0, sizeof(float) * DD, stream);
    }
    gather_update_kernel<<<2048, 256, 0, stream>>>(
        off, edata, hl, bond_emb + l * 3 * 8 * DD, root + l * DD, degrecip, h,
        bn_sum, bn_sq, do_stats);
    if (do_stats) {
      bn_finalize_kernel<<<1, DD, 0, stream>>>(bn_sum, bn_sq, gamma + l * DD,
                                               beta + l * DD, bsc, bsh);
    }
  }

  pool_mlp_kernel<<<NG, DD, 0, stream>>>(h, gstart, W1, b1, W2, b2, out);
}

// Round 3
// 975.611 us; speedup vs baseline: 2.1363x; 1.0989x over previous
//
#include <hip/hip_runtime.h>

#define NN 100000
#define NE 800000
#define DD 128
#define NL 4
#define NG 512
#define NT 10
#define BN_EPS 1e-5f
#define SCAN_B 1024

__device__ __forceinline__ float atomAddF(float* p, float v) {
  return unsafeAtomicAdd(p, v);
}

// ---------------- setup kernels ----------------

__global__ __launch_bounds__(256) void atom_encoder_kernel(
    const int* __restrict__ x, const float* __restrict__ atom_emb,
    float* __restrict__ h) {
  int idx = blockIdx.x * 256 + threadIdx.x;
  int n = idx >> 5, q = idx & 31;
  if (n >= NN) return;
  const int* xr = x + n * 9;
  float4 acc = make_float4(0.f, 0.f, 0.f, 0.f);
#pragma unroll
  for (int f = 0; f < 9; ++f) {
    const float4 v =
        *reinterpret_cast<const float4*>(&atom_emb[(f * 64 + xr[f]) * DD + q * 4]);
    acc.x += v.x; acc.y += v.y; acc.z += v.z; acc.w += v.w;
  }
  *reinterpret_cast<float4*>(&h[n * DD + q * 4]) = acc;
}

__global__ __launch_bounds__(256) void count_kernel(
    const int* __restrict__ idxs, int* __restrict__ cnt, int n) {
  int e = blockIdx.x * 256 + threadIdx.x;
  if (e < n) atomicAdd(&cnt[idxs[e]], 1);
}

__global__ __launch_bounds__(256) void deg_fin_kernel(
    const int* __restrict__ degcnt, float* __restrict__ degrecip,
    float* __restrict__ dinv) {
  int n = blockIdx.x * 256 + threadIdx.x;
  if (n < NN) {
    float dv = (float)degcnt[n] + 1.f;
    degrecip[n] = 1.f / dv;
    dinv[n] = rsqrtf(dv);
  }
}

// ---------------- CSR build ----------------

__global__ __launch_bounds__(256) void scan1_kernel(
    const int* __restrict__ in, int* __restrict__ out, int* __restrict__ bsum,
    int n) {
  __shared__ int s[256];
  int base = blockIdx.x * SCAN_B + threadIdx.x * 4;
  int v[4] = {0, 0, 0, 0};
  if (base + 3 < n) {
    int4 t = *reinterpret_cast<const int4*>(&in[base]);
    v[0] = t.x; v[1] = t.y; v[2] = t.z; v[3] = t.w;
  } else {
    for (int i = 0; i < 4; ++i) v[i] = (base + i < n) ? in[base + i] : 0;
  }
  int tsum = v[0] + v[1] + v[2] + v[3];
  s[threadIdx.x] = tsum;
  __syncthreads();
  for (int d = 1; d < 256; d <<= 1) {
    int t = (threadIdx.x >= d) ? s[threadIdx.x - d] : 0;
    __syncthreads();
    s[threadIdx.x] += t;
    __syncthreads();
  }
  int run = s[threadIdx.x] - tsum;
  if (threadIdx.x == 255) bsum[blockIdx.x] = s[255];
  for (int i = 0; i < 4; ++i) {
    if (base + i < n) out[base + i] = run;
    run += v[i];
  }
}

__global__ void scan2_kernel(int* bsum, int nb) {
  __shared__ int s[128];
  int v = (threadIdx.x < nb) ? bsum[threadIdx.x] : 0;
  s[threadIdx.x] = v;
  __syncthreads();
  for (int d = 1; d < 128; d <<= 1) {
    int t = (threadIdx.x >= d) ? s[threadIdx.x - d] : 0;
    __syncthreads();
    s[threadIdx.x] += t;
    __syncthreads();
  }
  if (threadIdx.x < nb) bsum[threadIdx.x] = s[threadIdx.x] - v;
}

__global__ __launch_bounds__(256) void scan3_kernel(int* off, const int* bsum,
                                                    int n, int total) {
  int i = blockIdx.x * 256 + threadIdx.x;
  if (i < n) off[i] += bsum[i / SCAN_B];
  if (i == 0) off[n] = total;
}

// packed edge record: {src | a0<<17 | a1<<20 | a2<<23, norm_bits}
__global__ __launch_bounds__(256) void csr_fill_kernel(
    const int* __restrict__ ei, const int* __restrict__ eattr,
    const float* __restrict__ dinv, const int* __restrict__ off,
    int* __restrict__ cursor, int2* __restrict__ edata) {
  int e = blockIdx.x * 256 + threadIdx.x;
  if (e >= NE) return;
  int r = ei[e], c = ei[NE + e];
  int pos = atomicAdd(&cursor[c], 1);
  float nm = dinv[r] * dinv[c];
  int2 d;
  d.x = r | (eattr[e * 3] << 17) | (eattr[e * 3 + 1] << 20) |
        (eattr[e * 3 + 2] << 23);
  d.y = __float_as_int(nm);
  edata[off[c] + pos] = d;
}

__global__ void gscan_kernel(const int* __restrict__ gcount,
                             int* __restrict__ gstart) {
  __shared__ int s[NG];
  int v = gcount[threadIdx.x];
  s[threadIdx.x] = v;
  __syncthreads();
  for (int d = 1; d < NG; d <<= 1) {
    int t = (threadIdx.x >= d) ? s[threadIdx.x - d] : 0;
    __syncthreads();
    s[threadIdx.x] += t;
    __syncthreads();
  }
  gstart[threadIdx.x] = s[threadIdx.x] - v;
  if (threadIdx.x == NG - 1) gstart[NG] = s[NG - 1];
}

// ---------------- GEMM v2: C = act(A) @ W + bias ----------------
// 128-row tile, BK=32 chunks, A row-major in LDS, 16x4 acc per thread.

#define BR 128
#define BK 32

__global__ __launch_bounds__(256) void gemm_bias_kernel(
    const float* __restrict__ A, const float* __restrict__ W,
    const float* __restrict__ bias, const float* __restrict__ bn_scale,
    const float* __restrict__ bn_shift, int fuse_bn, float* __restrict__ C) {
  __shared__ float As[BR][BK + 4];   // stride 36 floats: 16B-aligned rows
  __shared__ float Ws[BK][DD];
  __shared__ float sc_s[DD], sh_s[DD];
  const int t = threadIdx.x;
  if (t < DD) {
    sc_s[t] = fuse_bn ? bn_scale[t] : 1.f;
    sh_s[t] = fuse_bn ? bn_shift[t] : 0.f;
  }
  const int row0 = blockIdx.x * BR;
  const int tx4 = (t & 31) * 4;     // 4 output cols
  const int ty16 = (t >> 5) * 16;   // 16 output rows
  float acc[16][4] = {};
  const int sr = t >> 3;            // staging row (0..31, +32 per pass)
  const int sk = (t & 7) * 4;       // staging k offset
  const int wr = t >> 5;            // W staging row (0..7, +8 per pass)
  const int wc = (t & 31) * 4;
  __syncthreads();

  for (int c0 = 0; c0 < DD; c0 += BK) {
    __syncthreads();
#pragma unroll
    for (int p = 0; p < 4; ++p) {
      int r = sr + p * 32;
      int grow = row0 + r;
      float4 a4 = make_float4(0.f, 0.f, 0.f, 0.f);
      if (grow < NN)
        a4 = *reinterpret_cast<const float4*>(&A[grow * DD + c0 + sk]);
      if (fuse_bn) {
        a4.x = fmaxf(a4.x * sc_s[c0 + sk + 0] + sh_s[c0 + sk + 0], 0.f);
        a4.y = fmaxf(a4.y * sc_s[c0 + sk + 1] + sh_s[c0 + sk + 1], 0.f);
        a4.z = fmaxf(a4.z * sc_s[c0 + sk + 2] + sh_s[c0 + sk + 2], 0.f);
        a4.w = fmaxf(a4.w * sc_s[c0 + sk + 3] + sh_s[c0 + sk + 3], 0.f);
      }
      *reinterpret_cast<float4*>(&As[r][sk]) = a4;
    }
#pragma unroll
    for (int p = 0; p < 4; ++p) {
      int kr = wr + p * 8;
      *reinterpret_cast<float4*>(&Ws[kr][wc]) =
          *reinterpret_cast<const float4*>(&W[(c0 + kr) * DD + wc]);
    }
    __syncthreads();

    for (int kk = 0; kk < BK; kk += 4) {
      float4 w0 = *reinterpret_cast<const float4*>(&Ws[kk + 0][tx4]);
      float4 w1 = *reinterpret_cast<const float4*>(&Ws[kk + 1][tx4]);
      float4 w2 = *reinterpret_cast<const float4*>(&Ws[kk + 2][tx4]);
      float4 w3 = *reinterpret_cast<const float4*>(&Ws[kk + 3][tx4]);
#pragma unroll
      for (int i = 0; i < 16; ++i) {
        float4 a4 = *reinterpret_cast<const float4*>(&As[ty16 + i][kk]);
        acc[i][0] = fmaf(a4.x, w0.x, acc[i][0]);
        acc[i][1] = fmaf(a4.x, w0.y, acc[i][1]);
        acc[i][2] = fmaf(a4.x, w0.z, acc[i][2]);
        acc[i][3] = fmaf(a4.x, w0.w, acc[i][3]);
        acc[i][0] = fmaf(a4.y, w1.x, acc[i][0]);
        acc[i][1] = fmaf(a4.y, w1.y, acc[i][1]);
        acc[i][2] = fmaf(a4.y, w1.z, acc[i][2]);
        acc[i][3] = fmaf(a4.y, w1.w, acc[i][3]);
        acc[i][0] = fmaf(a4.z, w2.x, acc[i][0]);
        acc[i][1] = fmaf(a4.z, w2.y, acc[i][1]);
        acc[i][2] = fmaf(a4.z, w2.z, acc[i][2]);
        acc[i][3] = fmaf(a4.z, w2.w, acc[i][3]);
        acc[i][0] = fmaf(a4.w, w3.x, acc[i][0]);
        acc[i][1] = fmaf(a4.w, w3.y, acc[i][1]);
        acc[i][2] = fmaf(a4.w, w3.z, acc[i][2]);
        acc[i][3] = fmaf(a4.w, w3.w, acc[i][3]);
      }
    }
  }

  float4 b4 = *reinterpret_cast<const float4*>(&bias[tx4]);
#pragma unroll
  for (int i = 0; i < 16; ++i) {
    int grow = row0 + ty16 + i;
    if (grow < NN) {
      float4 o;
      o.x = acc[i][0] + b4.x;
      o.y = acc[i][1] + b4.y;
      o.z = acc[i][2] + b4.z;
      o.w = acc[i][3] + b4.w;
      *reinterpret_cast<float4*>(&C[grow * DD + tx4]) = o;
    }
  }
}

// ---------------- fused gather + update + BN stats ----------------

#define PROC(E)                                                              \
  {                                                                          \
    int p_ = (E).x;                                                          \
    float nm_ = __int_as_float((E).y);                                       \
    int r_ = p_ & 0x1FFFF;                                                   \
    int a0_ = (p_ >> 17) & 7, a1_ = (p_ >> 20) & 7, a2_ = (p_ >> 23) & 7;    \
    float be0 = bembS[a0_ * DD + d0] + bembS[(8 + a1_) * DD + d0] +          \
                bembS[(16 + a2_) * DD + d0];                                 \
    float be1 = bembS[a0_ * DD + d1] + bembS[(8 + a1_) * DD + d1] +          \
                bembS[(16 + a2_) * DD + d1];                                 \
    acc0 += nm_ * fmaxf(hl[r_ * DD + d0] + be0, 0.f);                        \
    acc1 += nm_ * fmaxf(hl[r_ * DD + d1] + be1, 0.f);                        \
  }

__global__ __launch_bounds__(256) void gather_update_kernel(
    const int* __restrict__ off, const int2* __restrict__ edata,
    const float* __restrict__ hl, const float* __restrict__ bemb,
    const float* __restrict__ root, const float* __restrict__ degrecip,
    float* __restrict__ h, float* __restrict__ bn_sum,
    float* __restrict__ bn_sq, int do_stats) {
  __shared__ float bembS[24 * DD];
  for (int i = threadIdx.x; i < 24 * DD; i += 256) bembS[i] = bemb[i];
  int wid = threadIdx.x >> 6;
  int lane = threadIdx.x & 63;
  int d0 = lane, d1 = lane + 64;
  float rt0 = root[d0], rt1 = root[d1];
  float ls0 = 0, ls1 = 0, lq0 = 0, lq1 = 0;
  __syncthreads();
  for (int n = blockIdx.x * 4 + wid; n < NN; n += gridDim.x * 4) {
    int k0 = off[n], k1 = off[n + 1];
    float acc0 = 0.f, acc1 = 0.f;
    int k = k0;
    for (; k + 3 < k1; k += 4) {
      int2 e0 = edata[k], e1 = edata[k + 1], e2 = edata[k + 2],
           e3 = edata[k + 3];
      PROC(e0) PROC(e1) PROC(e2) PROC(e3)
    }
    for (; k < k1; ++k) {
      int2 e0 = edata[k];
      PROC(e0)
    }
    float dr = degrecip[n];
    float v0 = acc0 + fmaxf(hl[n * DD + d0] + rt0, 0.f) * dr;
    float v1 = acc1 + fmaxf(hl[n * DD + d1] + rt1, 0.f) * dr;
    h[n * DD + d0] = v0;
    h[n * DD + d1] = v1;
    ls0 += v0; ls1 += v1;
    lq0 += v0 * v0; lq1 += v1 * v1;
  }
  if (do_stats) {
    __shared__ float s0[DD], s1[DD];
    if (wid == 0) {
      s0[d0] = ls0; s0[d1] = ls1;
      s1[d0] = lq0; s1[d1] = lq1;
    }
    __syncthreads();
#pragma unroll
    for (int w = 1; w < 4; ++w) {
      if (wid == w) {
        s0[d0] += ls0; s0[d1] += ls1;
        s1[d0] += lq0; s1[d1] += lq1;
      }
      __syncthreads();
    }
    if (threadIdx.x < DD) {
      atomAddF(&bn_sum[threadIdx.x], s0[threadIdx.x]);
      atomAddF(&bn_sq[threadIdx.x], s1[threadIdx.x]);
    }
  }
}

__global__ __launch_bounds__(128) void bn_finalize_kernel(
    const float* __restrict__ bn_sum, const float* __restrict__ bn_sq,
    const float* __restrict__ gamma, const float* __restrict__ beta,
    float* __restrict__ scale, float* __restrict__ shift) {
  int d = threadIdx.x;
  float mu = bn_sum[d] / (float)NN;
  float var = bn_sq[d] / (float)NN - mu * mu;
  float inv = rsqrtf(var + BN_EPS);
  float sc = gamma[d] * inv;
  scale[d] = sc;
  shift[d] = beta[d] - mu * sc;
}

// ---------------- pool (sorted batch, segmented) + MLP ----------------

__global__ __launch_bounds__(128) void pool_mlp_kernel(
    const float* __restrict__ h, const int* __restrict__ gstart,
    const float* __restrict__ W1, const float* __restrict__ b1,
    const float* __restrict__ W2, const float* __restrict__ b2,
    float* __restrict__ out) {
  int g = blockIdx.x, t = threadIdx.x;
  int s = gstart[g], e = gstart[g + 1];
  float acc = 0.f;
  for (int n = s; n < e; ++n) acc += h[n * DD + t];
  float cnt = fmaxf((float)(e - s), 1.f);
  __shared__ float row[DD], t1[DD];
  row[t] = fmaxf(acc / cnt, 0.f);
  __syncthreads();
  float a1v = b1[t];
  for (int k = 0; k < DD; ++k) a1v = fmaf(row[k], W1[k * DD + t], a1v);
  t1[t] = fmaxf(a1v, 0.f);
  __syncthreads();
  if (t < NT) {
    float a2 = b2[t];
    for (int k = 0; k < DD; ++k) a2 = fmaf(t1[k], W2[k * NT + t], a2);
    out[g * NT + t] = a2;
  }
}

extern "C" void kernel_launch(void* const* d_in, const int* in_sizes, int n_in,
                              void* d_out, int out_size, void* d_ws,
                              size_t ws_size, hipStream_t stream) {
  const int* x = (const int*)d_in[0];
  const int* edge_index = (const int*)d_in[1];
  const int* batch = (const int*)d_in[2];
  const int* edge_attr = (const int*)d_in[3];
  const float* atom_emb = (const float*)d_in[4];
  const float* W = (const float*)d_in[5];
  const float* b = (const float*)d_in[6];
  const float* root = (const float*)d_in[7];
  const float* bond_emb = (const float*)d_in[8];
  const float* gamma = (const float*)d_in[9];
  const float* beta = (const float*)d_in[10];
  const float* W1 = (const float*)d_in[11];
  const float* b1 = (const float*)d_in[12];
  const float* W2 = (const float*)d_in[13];
  const float* b2 = (const float*)d_in[14];
  float* out = (float*)d_out;

  char* ws = (char*)d_ws;
  size_t off_b = 0;
  auto alloc = [&](size_t bytes) {
    char* p = ws + off_b;
    off_b += (bytes + 255) & ~size_t(255);
    return p;
  };
  float* h = (float*)alloc(sizeof(float) * NN * DD);
  float* hl = (float*)alloc(sizeof(float) * NN * DD);
  int2* edata = (int2*)alloc(sizeof(int2) * NE);
  float* degrecip = (float*)alloc(sizeof(float) * NN);
  float* dinv = (float*)alloc(sizeof(float) * NN);
  int* degcnt = (int*)alloc(sizeof(int) * NN);
  int* incnt = (int*)alloc(sizeof(int) * NN);
  int* off = (int*)alloc(sizeof(int) * (NN + 1));
  int* cursor = (int*)alloc(sizeof(int) * NN);
  int* bsum = (int*)alloc(sizeof(int) * 128);
  float* bn_sum = (float*)alloc(sizeof(float) * DD);
  float* bn_sq = (float*)alloc(sizeof(float) * DD);
  float* bsc = (float*)alloc(sizeof(float) * DD);
  float* bsh = (float*)alloc(sizeof(float) * DD);
  int* gcount = (int*)alloc(sizeof(int) * NG);
  int* gstart = (int*)alloc(sizeof(int) * (NG + 1));

  hipMemsetAsync(degcnt, 0, sizeof(int) * NN, stream);
  hipMemsetAsync(incnt, 0, sizeof(int) * NN, stream);
  hipMemsetAsync(cursor, 0, sizeof(int) * NN, stream);
  hipMemsetAsync(gcount, 0, sizeof(int) * NG, stream);

  atom_encoder_kernel<<<(NN * 32 + 255) / 256, 256, 0, stream>>>(x, atom_emb, h);
  count_kernel<<<(NE + 255) / 256, 256, 0, stream>>>(edge_index, degcnt, NE);
  count_kernel<<<(NE + 255) / 256, 256, 0, stream>>>(edge_index + NE, incnt, NE);
  count_kernel<<<(NN + 255) / 256, 256, 0, stream>>>(batch, gcount, NN);
  deg_fin_kernel<<<(NN + 255) / 256, 256, 0, stream>>>(degcnt, degrecip, dinv);

  const int nb = (NN + SCAN_B - 1) / SCAN_B;  // 98
  scan1_kernel<<<nb, 256, 0, stream>>>(incnt, off, bsum, NN);
  scan2_kernel<<<1, 128, 0, stream>>>(bsum, nb);
  scan3_kernel<<<(NN + 255) / 256, 256, 0, stream>>>(off, bsum, NN, NE);
  csr_fill_kernel<<<(NE + 255) / 256, 256, 0, stream>>>(edge_index, edge_attr,
                                                        dinv, off, cursor, edata);
  gscan_kernel<<<1, NG, 0, stream>>>(gcount, gstart);

  for (int l = 0; l < NL; ++l) {
    gemm_bias_kernel<<<(NN + BR - 1) / BR, 256, 0, stream>>>(
        h, W + l * DD * DD, b + l * DD, bsc, bsh, l > 0 ? 1 : 0, hl);
    int do_stats = (l < NL - 1) ? 1 : 0;
    if (do_stats) {
      hipMemsetAsync(bn_sum, 0, sizeof(float) * DD, stream);
      hipMemsetAsync(bn_sq, 0, sizeof(float) * DD, stream);
    }
    gather_update_kernel<<<2048, 256, 0, stream>>>(
        off, edata, hl, bond_emb + l * 3 * 8 * DD, root + l * DD, degrecip, h,
        bn_sum, bn_sq, do_stats);
    if (do_stats) {
      bn_finalize_kernel<<<1, DD, 0, stream>>>(bn_sum, bn_sq, gamma + l * DD,
                                               beta + l * DD, bsc, bsh);
    }
  }

  pool_mlp_kernel<<<NG, DD, 0, stream>>>(h, gstart, W1, b1, W2, b2, out);
}

// Round 4
// 843.107 us; speedup vs baseline: 2.4721x; 1.1572x over previous
//
#include <hip/hip_runtime.h>
#include <hip/hip_fp16.h>

#define NN 100000
#define NE 800000
#define DD 128
#define NL 4
#define NG 512
#define NT 10
#define BN_EPS 1e-5f
#define SCAN_B 1024
#define CHUNK 13

__device__ __forceinline__ float atomAddF(float* p, float v) {
  return unsafeAtomicAdd(p, v);
}

// ---------------- setup kernels ----------------

__global__ __launch_bounds__(256) void atom_encoder_kernel(
    const int* __restrict__ x, const float* __restrict__ atom_emb,
    float* __restrict__ h) {
  int idx = blockIdx.x * 256 + threadIdx.x;
  int n = idx >> 5, q = idx & 31;
  if (n >= NN) return;
  const int* xr = x + n * 9;
  float4 acc = make_float4(0.f, 0.f, 0.f, 0.f);
#pragma unroll
  for (int f = 0; f < 9; ++f) {
    const float4 v =
        *reinterpret_cast<const float4*>(&atom_emb[(f * 64 + xr[f]) * DD + q * 4]);
    acc.x += v.x; acc.y += v.y; acc.z += v.z; acc.w += v.w;
  }
  *reinterpret_cast<float4*>(&h[n * DD + q * 4]) = acc;
}

__global__ __launch_bounds__(256) void edge_count_kernel(
    const int* __restrict__ ei, int* __restrict__ degcnt,
    int* __restrict__ incnt) {
  int e = blockIdx.x * 256 + threadIdx.x;
  if (e < NE) {
    atomicAdd(&degcnt[ei[e]], 1);
    atomicAdd(&incnt[ei[NE + e]], 1);
  }
}

__global__ __launch_bounds__(256) void count_kernel(
    const int* __restrict__ idxs, int* __restrict__ cnt, int n) {
  int e = blockIdx.x * 256 + threadIdx.x;
  if (e < n) atomicAdd(&cnt[idxs[e]], 1);
}

__global__ __launch_bounds__(256) void deg_fin_kernel(
    const int* __restrict__ degcnt, float* __restrict__ degrecip,
    float* __restrict__ dinv) {
  int n = blockIdx.x * 256 + threadIdx.x;
  if (n < NN) {
    float dv = (float)degcnt[n] + 1.f;
    degrecip[n] = 1.f / dv;
    dinv[n] = rsqrtf(dv);
  }
}

// ---------------- CSR build ----------------

__global__ __launch_bounds__(256) void scan1_kernel(
    const int* __restrict__ in, int* __restrict__ out, int* __restrict__ bsum,
    int n) {
  __shared__ int s[256];
  int base = blockIdx.x * SCAN_B + threadIdx.x * 4;
  int v[4] = {0, 0, 0, 0};
  if (base + 3 < n) {
    int4 t = *reinterpret_cast<const int4*>(&in[base]);
    v[0] = t.x; v[1] = t.y; v[2] = t.z; v[3] = t.w;
  } else {
    for (int i = 0; i < 4; ++i) v[i] = (base + i < n) ? in[base + i] : 0;
  }
  int tsum = v[0] + v[1] + v[2] + v[3];
  s[threadIdx.x] = tsum;
  __syncthreads();
  for (int d = 1; d < 256; d <<= 1) {
    int t = (threadIdx.x >= d) ? s[threadIdx.x - d] : 0;
    __syncthreads();
    s[threadIdx.x] += t;
    __syncthreads();
  }
  int run = s[threadIdx.x] - tsum;
  if (threadIdx.x == 255) bsum[blockIdx.x] = s[255];
  for (int i = 0; i < 4; ++i) {
    if (base + i < n) out[base + i] = run;
    run += v[i];
  }
}

__global__ void scan2_kernel(int* bsum, int nb) {
  __shared__ int s[128];
  int v = (threadIdx.x < nb) ? bsum[threadIdx.x] : 0;
  s[threadIdx.x] = v;
  __syncthreads();
  for (int d = 1; d < 128; d <<= 1) {
    int t = (threadIdx.x >= d) ? s[threadIdx.x - d] : 0;
    __syncthreads();
    s[threadIdx.x] += t;
    __syncthreads();
  }
  if (threadIdx.x < nb) bsum[threadIdx.x] = s[threadIdx.x] - v;
}

__global__ __launch_bounds__(256) void scan3_kernel(int* off, const int* bsum,
                                                    int n, int total) {
  int i = blockIdx.x * 256 + threadIdx.x;
  if (i < n) off[i] += bsum[i / SCAN_B];
  if (i == 0) off[n] = total;
}

// packed edge record: {src | a0<<17 | a1<<20 | a2<<23, norm_bits}
__global__ __launch_bounds__(256) void csr_fill_kernel(
    const int* __restrict__ ei, const int* __restrict__ eattr,
    const float* __restrict__ dinv, const int* __restrict__ off,
    int* __restrict__ cursor, int2* __restrict__ edata) {
  int e = blockIdx.x * 256 + threadIdx.x;
  if (e >= NE) return;
  int r = ei[e], c = ei[NE + e];
  int pos = atomicAdd(&cursor[c], 1);
  float nm = dinv[r] * dinv[c];
  int2 d;
  d.x = r | (eattr[e * 3] << 17) | (eattr[e * 3 + 1] << 20) |
        (eattr[e * 3 + 2] << 23);
  d.y = __float_as_int(nm);
  edata[off[c] + pos] = d;
}

__global__ void gscan_kernel(const int* __restrict__ gcount,
                             int* __restrict__ gstart) {
  __shared__ int s[NG];
  int v = gcount[threadIdx.x];
  s[threadIdx.x] = v;
  __syncthreads();
  for (int d = 1; d < NG; d <<= 1) {
    int t = (threadIdx.x >= d) ? s[threadIdx.x - d] : 0;
    __syncthreads();
    s[threadIdx.x] += t;
    __syncthreads();
  }
  gstart[threadIdx.x] = s[threadIdx.x] - v;
  if (threadIdx.x == NG - 1) gstart[NG] = s[NG - 1];
}

// ---------------- GEMM: hl_fp16 = act(A) @ W + bias ----------------
// 128-row tile, BK=32 chunks, software-pipelined staging, fp16 output.

#define BR 128
#define BK 32

__global__ __launch_bounds__(256) void gemm_bias_kernel(
    const float* __restrict__ A, const float* __restrict__ W,
    const float* __restrict__ bias, const float* __restrict__ bn_scale,
    const float* __restrict__ bn_shift, int fuse_bn, __half* __restrict__ hl) {
  __shared__ float As[BR][BK + 4];
  __shared__ float Ws[BK][DD];
  __shared__ float sc_s[DD], sh_s[DD];
  const int t = threadIdx.x;
  if (t < DD) {
    sc_s[t] = fuse_bn ? bn_scale[t] : 1.f;
    sh_s[t] = fuse_bn ? bn_shift[t] : 0.f;
  }
  const int row0 = blockIdx.x * BR;
  const int tx4 = (t & 31) * 4;
  const int ty16 = (t >> 5) * 16;
  const int sr = t >> 3;            // A staging row base (0..31)
  const int sk = (t & 7) * 4;       // A staging k offset
  const int wr = t >> 5;            // W staging row base (0..7)
  const int wc = (t & 31) * 4;
  float acc[16][4] = {};
  float4 aR[4], wR[4];

#pragma unroll
  for (int p = 0; p < 4; ++p) {
    int grow = row0 + sr + p * 32;
    aR[p] = (grow < NN) ? *reinterpret_cast<const float4*>(&A[grow * DD + sk])
                        : make_float4(0.f, 0.f, 0.f, 0.f);
    wR[p] = *reinterpret_cast<const float4*>(&W[(wr + p * 8) * DD + wc]);
  }
  __syncthreads();  // sc_s ready

  for (int c0 = 0; c0 < DD; c0 += BK) {
    if (c0) __syncthreads();  // previous compute done
#pragma unroll
    for (int p = 0; p < 4; ++p) {
      float4 a4 = aR[p];
      if (fuse_bn) {
        a4.x = fmaxf(a4.x * sc_s[c0 + sk + 0] + sh_s[c0 + sk + 0], 0.f);
        a4.y = fmaxf(a4.y * sc_s[c0 + sk + 1] + sh_s[c0 + sk + 1], 0.f);
        a4.z = fmaxf(a4.z * sc_s[c0 + sk + 2] + sh_s[c0 + sk + 2], 0.f);
        a4.w = fmaxf(a4.w * sc_s[c0 + sk + 3] + sh_s[c0 + sk + 3], 0.f);
      }
      *reinterpret_cast<float4*>(&As[sr + p * 32][sk]) = a4;
      *reinterpret_cast<float4*>(&Ws[wr + p * 8][wc]) = wR[p];
    }
    __syncthreads();
    if (c0 + BK < DD) {
      int c1 = c0 + BK;
#pragma unroll
      for (int p = 0; p < 4; ++p) {
        int grow = row0 + sr + p * 32;
        aR[p] = (grow < NN)
                    ? *reinterpret_cast<const float4*>(&A[grow * DD + c1 + sk])
                    : make_float4(0.f, 0.f, 0.f, 0.f);
        wR[p] = *reinterpret_cast<const float4*>(&W[(c1 + wr + p * 8) * DD + wc]);
      }
    }
    for (int kk = 0; kk < BK; kk += 4) {
      float4 w0 = *reinterpret_cast<const float4*>(&Ws[kk + 0][tx4]);
      float4 w1 = *reinterpret_cast<const float4*>(&Ws[kk + 1][tx4]);
      float4 w2 = *reinterpret_cast<const float4*>(&Ws[kk + 2][tx4]);
      float4 w3 = *reinterpret_cast<const float4*>(&Ws[kk + 3][tx4]);
#pragma unroll
      for (int i = 0; i < 16; ++i) {
        float4 a4 = *reinterpret_cast<const float4*>(&As[ty16 + i][kk]);
        acc[i][0] = fmaf(a4.x, w0.x, acc[i][0]);
        acc[i][1] = fmaf(a4.x, w0.y, acc[i][1]);
        acc[i][2] = fmaf(a4.x, w0.z, acc[i][2]);
        acc[i][3] = fmaf(a4.x, w0.w, acc[i][3]);
        acc[i][0] = fmaf(a4.y, w1.x, acc[i][0]);
        acc[i][1] = fmaf(a4.y, w1.y, acc[i][1]);
        acc[i][2] = fmaf(a4.y, w1.z, acc[i][2]);
        acc[i][3] = fmaf(a4.y, w1.w, acc[i][3]);
        acc[i][0] = fmaf(a4.z, w2.x, acc[i][0]);
        acc[i][1] = fmaf(a4.z, w2.y, acc[i][1]);
        acc[i][2] = fmaf(a4.z, w2.z, acc[i][2]);
        acc[i][3] = fmaf(a4.z, w2.w, acc[i][3]);
        acc[i][0] = fmaf(a4.w, w3.x, acc[i][0]);
        acc[i][1] = fmaf(a4.w, w3.y, acc[i][1]);
        acc[i][2] = fmaf(a4.w, w3.z, acc[i][2]);
        acc[i][3] = fmaf(a4.w, w3.w, acc[i][3]);
      }
    }
  }

  float4 b4 = *reinterpret_cast<const float4*>(&bias[tx4]);
#pragma unroll
  for (int i = 0; i < 16; ++i) {
    int grow = row0 + ty16 + i;
    if (grow < NN) {
      union {
        struct { __half2 a, b; } hh;
        int2 i2;
      } u;
      u.hh.a = __floats2half2_rn(acc[i][0] + b4.x, acc[i][1] + b4.y);
      u.hh.b = __floats2half2_rn(acc[i][2] + b4.z, acc[i][3] + b4.w);
      *reinterpret_cast<int2*>(&hl[grow * DD + tx4]) = u.i2;
    }
  }
}

// ---------------- fused gather + update + BN stats / pool ----------------
// one wave per contiguous CHUNK of nodes; lane owns channels {2l, 2l+1}

#define PROC(E)                                                           \
  {                                                                       \
    int p_ = (E).x;                                                       \
    float nm_ = __int_as_float((E).y);                                    \
    int r_ = p_ & 0x1FFFF;                                                \
    int a0_ = (p_ >> 17) & 7, a1_ = (p_ >> 20) & 7, a2_ = (p_ >> 23) & 7; \
    float2 b0_ = bembS[a0_ * 64 + lane];                                  \
    float2 b1_ = bembS[(8 + a1_) * 64 + lane];                            \
    float2 b2_ = bembS[(16 + a2_) * 64 + lane];                           \
    float2 hv_ = __half22float2(hl2[r_ * 64 + lane]);                     \
    acc0 += nm_ * fmaxf(hv_.x + b0_.x + b1_.x + b2_.x, 0.f);              \
    acc1 += nm_ * fmaxf(hv_.y + b0_.y + b1_.y + b2_.y, 0.f);              \
  }

__global__ __launch_bounds__(256) void gather_update_kernel(
    const int* __restrict__ off, const int2* __restrict__ edata,
    const __half2* __restrict__ hl2, const float* __restrict__ bemb,
    const float* __restrict__ root, const float* __restrict__ degrecip,
    const int* __restrict__ batch, float* __restrict__ h,
    float* __restrict__ hg, float* __restrict__ bn_sum,
    float* __restrict__ bn_sq, int mode) {  // mode 0: h+stats, 1: pool
  __shared__ float2 bembS[24 * 64];
  const float2* bemb2 = reinterpret_cast<const float2*>(bemb);
  for (int i = threadIdx.x; i < 24 * 64; i += 256) bembS[i] = bemb2[i];
  const int wid = threadIdx.x >> 6;
  const int lane = threadIdx.x & 63;
  float2 rt = *reinterpret_cast<const float2*>(&root[2 * lane]);
  float ls0 = 0, ls1 = 0, lq0 = 0, lq1 = 0;
  const int wv = blockIdx.x * 4 + wid;
  const int n0 = wv * CHUNK;
  const int n1 = min(n0 + CHUNK, NN);
  int curg = -1;
  float pg0 = 0.f, pg1 = 0.f;
  __syncthreads();
  for (int n = n0; n < n1; ++n) {
    int k0 = off[n], k1 = off[n + 1];
    float acc0 = 0.f, acc1 = 0.f;
    int k = k0;
    for (; k + 3 < k1; k += 4) {
      int2 e0 = edata[k], e1 = edata[k + 1], e2 = edata[k + 2],
           e3 = edata[k + 3];
      PROC(e0) PROC(e1) PROC(e2) PROC(e3)
    }
    for (; k < k1; ++k) {
      int2 e0 = edata[k];
      PROC(e0)
    }
    float dr = degrecip[n];
    float2 hs = __half22float2(hl2[n * 64 + lane]);
    float v0 = acc0 + fmaxf(hs.x + rt.x, 0.f) * dr;
    float v1 = acc1 + fmaxf(hs.y + rt.y, 0.f) * dr;
    if (mode == 0) {
      float2 o = make_float2(v0, v1);
      *reinterpret_cast<float2*>(&h[n * DD + 2 * lane]) = o;
      ls0 += v0; ls1 += v1;
      lq0 += v0 * v0; lq1 += v1 * v1;
    } else {
      int g = batch[n];
      if (g != curg) {
        if (curg >= 0) {
          atomAddF(&hg[curg * DD + 2 * lane], pg0);
          atomAddF(&hg[curg * DD + 2 * lane + 1], pg1);
        }
        curg = g;
        pg0 = v0; pg1 = v1;
      } else {
        pg0 += v0; pg1 += v1;
      }
    }
  }
  if (mode == 1) {
    if (curg >= 0) {
      atomAddF(&hg[curg * DD + 2 * lane], pg0);
      atomAddF(&hg[curg * DD + 2 * lane + 1], pg1);
    }
    return;
  }
  __shared__ float s0[DD], s1[DD];
  const int d0 = 2 * lane, d1 = 2 * lane + 1;
  if (wid == 0) {
    s0[d0] = ls0; s0[d1] = ls1;
    s1[d0] = lq0; s1[d1] = lq1;
  }
  __syncthreads();
#pragma unroll
  for (int w = 1; w < 4; ++w) {
    if (wid == w) {
      s0[d0] += ls0; s0[d1] += ls1;
      s1[d0] += lq0; s1[d1] += lq1;
    }
    __syncthreads();
  }
  if (threadIdx.x < DD) {
    atomAddF(&bn_sum[threadIdx.x], s0[threadIdx.x]);
    atomAddF(&bn_sq[threadIdx.x], s1[threadIdx.x]);
  }
}

__global__ __launch_bounds__(128) void bn_finalize_kernel(
    const float* __restrict__ bn_sum, const float* __restrict__ bn_sq,
    const float* __restrict__ gamma, const float* __restrict__ beta,
    float* __restrict__ scale, float* __restrict__ shift) {
  int d = threadIdx.x;
  float mu = bn_sum[d] / (float)NN;
  float var = bn_sq[d] / (float)NN - mu * mu;
  float inv = rsqrtf(var + BN_EPS);
  float sc = gamma[d] * inv;
  scale[d] = sc;
  shift[d] = beta[d] - mu * sc;
}

// ---------------- MLP on pooled features ----------------

__global__ __launch_bounds__(128) void mlp_kernel(
    const float* __restrict__ hg, const int* __restrict__ gstart,
    const float* __restrict__ W1, const float* __restrict__ b1,
    const float* __restrict__ W2, const float* __restrict__ b2,
    float* __restrict__ out) {
  int g = blockIdx.x, t = threadIdx.x;
  float cnt = fmaxf((float)(gstart[g + 1] - gstart[g]), 1.f);
  __shared__ float row[DD], t1[DD];
  row[t] = fmaxf(hg[g * DD + t] / cnt, 0.f);
  __syncthreads();
  float a1v = b1[t];
  for (int k = 0; k < DD; ++k) a1v = fmaf(row[k], W1[k * DD + t], a1v);
  t1[t] = fmaxf(a1v, 0.f);
  __syncthreads();
  if (t < NT) {
    float a2 = b2[t];
    for (int k = 0; k < DD; ++k) a2 = fmaf(t1[k], W2[k * NT + t], a2);
    out[g * NT + t] = a2;
  }
}

extern "C" void kernel_launch(void* const* d_in, const int* in_sizes, int n_in,
                              void* d_out, int out_size, void* d_ws,
                              size_t ws_size, hipStream_t stream) {
  const int* x = (const int*)d_in[0];
  const int* edge_index = (const int*)d_in[1];
  const int* batch = (const int*)d_in[2];
  const int* edge_attr = (const int*)d_in[3];
  const float* atom_emb = (const float*)d_in[4];
  const float* W = (const float*)d_in[5];
  const float* b = (const float*)d_in[6];
  const float* root = (const float*)d_in[7];
  const float* bond_emb = (const float*)d_in[8];
  const float* gamma = (const float*)d_in[9];
  const float* beta = (const float*)d_in[10];
  const float* W1 = (const float*)d_in[11];
  const float* b1 = (const float*)d_in[12];
  const float* W2 = (const float*)d_in[13];
  const float* b2 = (const float*)d_in[14];
  float* out = (float*)d_out;

  char* ws = (char*)d_ws;
  size_t off_b = 0;
  auto alloc = [&](size_t bytes) {
    char* p = ws + off_b;
    off_b += (bytes + 255) & ~size_t(255);
    return p;
  };
  float* h = (float*)alloc(sizeof(float) * NN * DD);
  __half* hl = (__half*)alloc(sizeof(__half) * NN * DD);
  int2* edata = (int2*)alloc(sizeof(int2) * NE);
  float* degrecip = (float*)alloc(sizeof(float) * NN);
  float* dinv = (float*)alloc(sizeof(float) * NN);
  int* degcnt = (int*)alloc(sizeof(int) * NN);
  int* incnt = (int*)alloc(sizeof(int) * NN);
  int* off = (int*)alloc(sizeof(int) * (NN + 1));
  int* cursor = (int*)alloc(sizeof(int) * NN);
  int* bsum = (int*)alloc(sizeof(int) * 128);
  float* bn_sum = (float*)alloc(sizeof(float) * DD);
  float* bn_sq = (float*)alloc(sizeof(float) * DD);
  float* bsc = (float*)alloc(sizeof(float) * DD);
  float* bsh = (float*)alloc(sizeof(float) * DD);
  int* gcount = (int*)alloc(sizeof(int) * NG);
  int* gstart = (int*)alloc(sizeof(int) * (NG + 1));
  float* hg = (float*)alloc(sizeof(float) * NG * DD);

  hipMemsetAsync(degcnt, 0, sizeof(int) * NN, stream);
  hipMemsetAsync(incnt, 0, sizeof(int) * NN, stream);
  hipMemsetAsync(cursor, 0, sizeof(int) * NN, stream);
  hipMemsetAsync(gcount, 0, sizeof(int) * NG, stream);
  hipMemsetAsync(hg, 0, sizeof(float) * NG * DD, stream);

  atom_encoder_kernel<<<(NN * 32 + 255) / 256, 256, 0, stream>>>(x, atom_emb, h);
  edge_count_kernel<<<(NE + 255) / 256, 256, 0, stream>>>(edge_index, degcnt,
                                                          incnt);
  count_kernel<<<(NN + 255) / 256, 256, 0, stream>>>(batch, gcount, NN);
  deg_fin_kernel<<<(NN + 255) / 256, 256, 0, stream>>>(degcnt, degrecip, dinv);

  const int nb = (NN + SCAN_B - 1) / SCAN_B;  // 98
  scan1_kernel<<<nb, 256, 0, stream>>>(incnt, off, bsum, NN);
  scan2_kernel<<<1, 128, 0, stream>>>(bsum, nb);
  scan3_kernel<<<(NN + 255) / 256, 256, 0, stream>>>(off, bsum, NN, NE);
  csr_fill_kernel<<<(NE + 255) / 256, 256, 0, stream>>>(edge_index, edge_attr,
                                                        dinv, off, cursor, edata);
  gscan_kernel<<<1, NG, 0, stream>>>(gcount, gstart);

  const int GB = (NN + 4 * CHUNK - 1) / (4 * CHUNK);  // 1924 blocks
  for (int l = 0; l < NL; ++l) {
    gemm_bias_kernel<<<(NN + BR - 1) / BR, 256, 0, stream>>>(
        h, W + l * DD * DD, b + l * DD, bsc, bsh, l > 0 ? 1 : 0, hl);
    int mode = (l < NL - 1) ? 0 : 1;
    if (mode == 0) {
      hipMemsetAsync(bn_sum, 0, sizeof(float) * DD, stream);
      hipMemsetAsync(bn_sq, 0, sizeof(float) * DD, stream);
    }
    gather_update_kernel<<<GB, 256, 0, stream>>>(
        off, edata, (const __half2*)hl, bond_emb + l * 3 * 8 * DD,
        root + l * DD, degrecip, batch, h, hg, bn_sum, bn_sq, mode);
    if (mode == 0) {
      bn_finalize_kernel<<<1, DD, 0, stream>>>(bn_sum, bn_sq, gamma + l * DD,
                                               beta + l * DD, bsc, bsh);
    }
  }

  mlp_kernel<<<NG, DD, 0, stream>>>(hg, gstart, W1, b1, W2, b2, out);
}

// Round 5
// 791.091 us; speedup vs baseline: 2.6346x; 1.0658x over previous
//
#include <hip/hip_runtime.h>
#include <hip/hip_fp16.h>

#define NN 100000
#define NE 800000
#define DD 128
#define NL 4
#define NG 512
#define NT 10
#define BN_EPS 1e-5f
#define SCAN_B 1024
#define CHUNK 13

typedef __attribute__((ext_vector_type(4))) float f32x4;
typedef __attribute__((ext_vector_type(8))) _Float16 f16x8;

__device__ __forceinline__ float atomAddF(float* p, float v) {
  return unsafeAtomicAdd(p, v);
}

// ---------------- setup kernels ----------------

__global__ __launch_bounds__(256) void atom_encoder_kernel(
    const int* __restrict__ x, const float* __restrict__ atom_emb,
    float* __restrict__ h) {
  int idx = blockIdx.x * 256 + threadIdx.x;
  int n = idx >> 5, q = idx & 31;
  if (n >= NN) return;
  const int* xr = x + n * 9;
  float4 acc = make_float4(0.f, 0.f, 0.f, 0.f);
#pragma unroll
  for (int f = 0; f < 9; ++f) {
    const float4 v =
        *reinterpret_cast<const float4*>(&atom_emb[(f * 64 + xr[f]) * DD + q * 4]);
    acc.x += v.x; acc.y += v.y; acc.z += v.z; acc.w += v.w;
  }
  *reinterpret_cast<float4*>(&h[n * DD + q * 4]) = acc;
}

__global__ __launch_bounds__(256) void edge_count_kernel(
    const int* __restrict__ ei, int* __restrict__ degcnt,
    int* __restrict__ incnt) {
  int e = blockIdx.x * 256 + threadIdx.x;
  if (e < NE) {
    atomicAdd(&degcnt[ei[e]], 1);
    atomicAdd(&incnt[ei[NE + e]], 1);
  }
}

__global__ __launch_bounds__(256) void count_kernel(
    const int* __restrict__ idxs, int* __restrict__ cnt, int n) {
  int e = blockIdx.x * 256 + threadIdx.x;
  if (e < n) atomicAdd(&cnt[idxs[e]], 1);
}

__global__ __launch_bounds__(256) void deg_fin_kernel(
    const int* __restrict__ degcnt, float* __restrict__ degrecip,
    float* __restrict__ dinv) {
  int n = blockIdx.x * 256 + threadIdx.x;
  if (n < NN) {
    float dv = (float)degcnt[n] + 1.f;
    degrecip[n] = 1.f / dv;
    dinv[n] = rsqrtf(dv);
  }
}

// W -> fragment-ordered fp16: Wf[l][tile(8)][chunk(4)][lane(64)][i(8)]
// frag value = W[l][chunk*32 + (lane>>4)*8 + i][tile*16 + (lane&15)]
__global__ __launch_bounds__(256) void wfrag_kernel(const float* __restrict__ W,
                                                    __half* __restrict__ Wf) {
  int idx = blockIdx.x * 256 + threadIdx.x;  // 4*8*4*64 = 8192
  if (idx >= NL * 8 * 4 * 64) return;
  int lane = idx & 63;
  int c = (idx >> 6) & 3;
  int t = (idx >> 8) & 7;
  int l = idx >> 11;
  const float* Wl = W + l * DD * DD;
  __half* o = Wf + idx * 8;
  int n = t * 16 + (lane & 15);
  int k0 = c * 32 + (lane >> 4) * 8;
#pragma unroll
  for (int i = 0; i < 8; ++i) o[i] = (__half)Wl[(k0 + i) * DD + n];
}

// ---------------- CSR build ----------------

__global__ __launch_bounds__(256) void scan1_kernel(
    const int* __restrict__ in, int* __restrict__ out, int* __restrict__ bsum,
    int n) {
  __shared__ int s[256];
  int base = blockIdx.x * SCAN_B + threadIdx.x * 4;
  int v[4] = {0, 0, 0, 0};
  if (base + 3 < n) {
    int4 t = *reinterpret_cast<const int4*>(&in[base]);
    v[0] = t.x; v[1] = t.y; v[2] = t.z; v[3] = t.w;
  } else {
    for (int i = 0; i < 4; ++i) v[i] = (base + i < n) ? in[base + i] : 0;
  }
  int tsum = v[0] + v[1] + v[2] + v[3];
  s[threadIdx.x] = tsum;
  __syncthreads();
  for (int d = 1; d < 256; d <<= 1) {
    int t = (threadIdx.x >= d) ? s[threadIdx.x - d] : 0;
    __syncthreads();
    s[threadIdx.x] += t;
    __syncthreads();
  }
  int run = s[threadIdx.x] - tsum;
  if (threadIdx.x == 255) bsum[blockIdx.x] = s[255];
  for (int i = 0; i < 4; ++i) {
    if (base + i < n) out[base + i] = run;
    run += v[i];
  }
}

__global__ void scan2_kernel(int* bsum, int nb) {
  __shared__ int s[128];
  int v = (threadIdx.x < nb) ? bsum[threadIdx.x] : 0;
  s[threadIdx.x] = v;
  __syncthreads();
  for (int d = 1; d < 128; d <<= 1) {
    int t = (threadIdx.x >= d) ? s[threadIdx.x - d] : 0;
    __syncthreads();
    s[threadIdx.x] += t;
    __syncthreads();
  }
  if (threadIdx.x < nb) bsum[threadIdx.x] = s[threadIdx.x] - v;
}

__global__ __launch_bounds__(256) void scan3_kernel(int* off, const int* bsum,
                                                    int n, int total) {
  int i = blockIdx.x * 256 + threadIdx.x;
  if (i < n) off[i] += bsum[i / SCAN_B];
  if (i == 0) off[n] = total;
}

// packed edge record: {src | a0<<17 | a1<<20 | a2<<23, norm_bits}
__global__ __launch_bounds__(256) void csr_fill_kernel(
    const int* __restrict__ ei, const int* __restrict__ eattr,
    const float* __restrict__ dinv, const int* __restrict__ off,
    int* __restrict__ cursor, int2* __restrict__ edata) {
  int e = blockIdx.x * 256 + threadIdx.x;
  if (e >= NE) return;
  int r = ei[e], c = ei[NE + e];
  int pos = atomicAdd(&cursor[c], 1);
  float nm = dinv[r] * dinv[c];
  int2 d;
  d.x = r | (eattr[e * 3] << 17) | (eattr[e * 3 + 1] << 20) |
        (eattr[e * 3 + 2] << 23);
  d.y = __float_as_int(nm);
  edata[off[c] + pos] = d;
}

__global__ void gscan_kernel(const int* __restrict__ gcount,
                             int* __restrict__ gstart) {
  __shared__ int s[NG];
  int v = gcount[threadIdx.x];
  s[threadIdx.x] = v;
  __syncthreads();
  for (int d = 1; d < NG; d <<= 1) {
    int t = (threadIdx.x >= d) ? s[threadIdx.x - d] : 0;
    __syncthreads();
    s[threadIdx.x] += t;
    __syncthreads();
  }
  gstart[threadIdx.x] = s[threadIdx.x] - v;
  if (threadIdx.x == NG - 1) gstart[NG] = s[NG - 1];
}

// ---------------- MFMA GEMM: hl = act(A) @ W + bias (fp16 out) ----------------
// 4 waves/block, wave owns 16 rows x 128 cols. No LDS, no barriers.
// A frag: lane holds row (lane&15), k = chunk*32 + (lane>>4)*8 + i
// C tile: col = lane&15, row = (lane>>4)*4 + reg

__global__ __launch_bounds__(256) void gemm_mfma_kernel(
    const float* __restrict__ A, const __half* __restrict__ Wf,
    const float* __restrict__ bias, const float* __restrict__ bn_scale,
    const float* __restrict__ bn_shift, int fuse_bn, __half* __restrict__ hl) {
  const int wid = threadIdx.x >> 6, lane = threadIdx.x & 63;
  const int r0 = blockIdx.x * 64 + wid * 16;
  const int arow = min(r0 + (lane & 15), NN - 1);
  const int kb = (lane >> 4) * 8;

  f16x8 afrag[4];
#pragma unroll
  for (int c = 0; c < 4; ++c) {
    const int k0 = c * 32 + kb;
    float4 x0 = *reinterpret_cast<const float4*>(&A[arow * DD + k0]);
    float4 x1 = *reinterpret_cast<const float4*>(&A[arow * DD + k0 + 4]);
    float v[8] = {x0.x, x0.y, x0.z, x0.w, x1.x, x1.y, x1.z, x1.w};
    if (fuse_bn) {
#pragma unroll
      for (int i = 0; i < 8; ++i)
        v[i] = fmaxf(v[i] * bn_scale[k0 + i] + bn_shift[k0 + i], 0.f);
    }
#pragma unroll
    for (int i = 0; i < 8; ++i) afrag[c][i] = (_Float16)v[i];
  }

  f32x4 acc[8];
#pragma unroll
  for (int t = 0; t < 8; ++t) acc[t] = (f32x4){0.f, 0.f, 0.f, 0.f};

  const f16x8* __restrict__ wf = reinterpret_cast<const f16x8*>(Wf);
#pragma unroll
  for (int t = 0; t < 8; ++t) {
#pragma unroll
    for (int c = 0; c < 4; ++c) {
      f16x8 b = wf[(t * 4 + c) * 64 + lane];
      acc[t] = __builtin_amdgcn_mfma_f32_16x16x32_f16(afrag[c], b, acc[t], 0, 0, 0);
    }
  }

  const int colb = lane & 15;
  const int rbase = r0 + (lane >> 4) * 4;
#pragma unroll
  for (int t = 0; t < 8; ++t) {
    float bb = bias[t * 16 + colb];
#pragma unroll
    for (int j = 0; j < 4; ++j) {
      int row = rbase + j;
      if (row < NN) hl[row * DD + t * 16 + colb] = (__half)(acc[t][j] + bb);
    }
  }
}

// ---------------- fused gather + update + BN stats / pool ----------------

#define PROC(E)                                                           \
  {                                                                       \
    int p_ = (E).x;                                                       \
    float nm_ = __int_as_float((E).y);                                    \
    int r_ = p_ & 0x1FFFF;                                                \
    int a0_ = (p_ >> 17) & 7, a1_ = (p_ >> 20) & 7, a2_ = (p_ >> 23) & 7; \
    float2 b0_ = bembS[a0_ * 64 + lane];                                  \
    float2 b1_ = bembS[(8 + a1_) * 64 + lane];                            \
    float2 b2_ = bembS[(16 + a2_) * 64 + lane];                           \
    float2 hv_ = __half22float2(hl2[r_ * 64 + lane]);                     \
    acc0 += nm_ * fmaxf(hv_.x + b0_.x + b1_.x + b2_.x, 0.f);              \
    acc1 += nm_ * fmaxf(hv_.y + b0_.y + b1_.y + b2_.y, 0.f);              \
  }

__global__ __launch_bounds__(256) void gather_update_kernel(
    const int* __restrict__ off, const int2* __restrict__ edata,
    const __half2* __restrict__ hl2, const float* __restrict__ bemb,
    const float* __restrict__ root, const float* __restrict__ degrecip,
    const int* __restrict__ batch, float* __restrict__ h,
    float* __restrict__ hg, float* __restrict__ bn_sum,
    float* __restrict__ bn_sq, int mode) {  // mode 0: h+stats, 1: pool
  __shared__ float2 bembS[24 * 64];
  const float2* bemb2 = reinterpret_cast<const float2*>(bemb);
  for (int i = threadIdx.x; i < 24 * 64; i += 256) bembS[i] = bemb2[i];
  const int wid = threadIdx.x >> 6;
  const int lane = threadIdx.x & 63;
  float2 rt = *reinterpret_cast<const float2*>(&root[2 * lane]);
  float ls0 = 0, ls1 = 0, lq0 = 0, lq1 = 0;
  const int wv = blockIdx.x * 4 + wid;
  const int n0 = wv * CHUNK;
  const int n1 = min(n0 + CHUNK, NN);
  int curg = -1;
  float pg0 = 0.f, pg1 = 0.f;
  __syncthreads();
  for (int n = n0; n < n1; ++n) {
    int k0 = off[n], k1 = off[n + 1];
    float acc0 = 0.f, acc1 = 0.f;
    int k = k0;
    for (; k + 7 < k1; k += 8) {
      int2 e0 = edata[k], e1 = edata[k + 1], e2 = edata[k + 2],
           e3 = edata[k + 3], e4 = edata[k + 4], e5 = edata[k + 5],
           e6 = edata[k + 6], e7 = edata[k + 7];
      PROC(e0) PROC(e1) PROC(e2) PROC(e3)
      PROC(e4) PROC(e5) PROC(e6) PROC(e7)
    }
    for (; k + 3 < k1; k += 4) {
      int2 e0 = edata[k], e1 = edata[k + 1], e2 = edata[k + 2],
           e3 = edata[k + 3];
      PROC(e0) PROC(e1) PROC(e2) PROC(e3)
    }
    for (; k < k1; ++k) {
      int2 e0 = edata[k];
      PROC(e0)
    }
    float dr = degrecip[n];
    float2 hs = __half22float2(hl2[n * 64 + lane]);
    float v0 = acc0 + fmaxf(hs.x + rt.x, 0.f) * dr;
    float v1 = acc1 + fmaxf(hs.y + rt.y, 0.f) * dr;
    if (mode == 0) {
      float2 o = make_float2(v0, v1);
      *reinterpret_cast<float2*>(&h[n * DD + 2 * lane]) = o;
      ls0 += v0; ls1 += v1;
      lq0 += v0 * v0; lq1 += v1 * v1;
    } else {
      int g = batch[n];
      if (g != curg) {
        if (curg >= 0) {
          atomAddF(&hg[curg * DD + 2 * lane], pg0);
          atomAddF(&hg[curg * DD + 2 * lane + 1], pg1);
        }
        curg = g;
        pg0 = v0; pg1 = v1;
      } else {
        pg0 += v0; pg1 += v1;
      }
    }
  }
  if (mode == 1) {
    if (curg >= 0) {
      atomAddF(&hg[curg * DD + 2 * lane], pg0);
      atomAddF(&hg[curg * DD + 2 * lane + 1], pg1);
    }
    return;
  }
  __shared__ float s0[DD], s1[DD];
  const int d0 = 2 * lane, d1 = 2 * lane + 1;
  if (wid == 0) {
    s0[d0] = ls0; s0[d1] = ls1;
    s1[d0] = lq0; s1[d1] = lq1;
  }
  __syncthreads();
#pragma unroll
  for (int w = 1; w < 4; ++w) {
    if (wid == w) {
      s0[d0] += ls0; s0[d1] += ls1;
      s1[d0] += lq0; s1[d1] += lq1;
    }
    __syncthreads();
  }
  if (threadIdx.x < DD) {
    atomAddF(&bn_sum[threadIdx.x], s0[threadIdx.x]);
    atomAddF(&bn_sq[threadIdx.x], s1[threadIdx.x]);
  }
}

__global__ __launch_bounds__(128) void bn_finalize_kernel(
    const float* __restrict__ bn_sum, const float* __restrict__ bn_sq,
    const float* __restrict__ gamma, const float* __restrict__ beta,
    float* __restrict__ scale, float* __restrict__ shift) {
  int d = threadIdx.x;
  float mu = bn_sum[d] / (float)NN;
  float var = bn_sq[d] / (float)NN - mu * mu;
  float inv = rsqrtf(var + BN_EPS);
  float sc = gamma[d] * inv;
  scale[d] = sc;
  shift[d] = beta[d] - mu * sc;
}

// ---------------- MLP on pooled features ----------------

__global__ __launch_bounds__(128) void mlp_kernel(
    const float* __restrict__ hg, const int* __restrict__ gstart,
    const float* __restrict__ W1, const float* __restrict__ b1,
    const float* __restrict__ W2, const float* __restrict__ b2,
    float* __restrict__ out) {
  int g = blockIdx.x, t = threadIdx.x;
  float cnt = fmaxf((float)(gstart[g + 1] - gstart[g]), 1.f);
  __shared__ float row[DD], t1[DD];
  row[t] = fmaxf(hg[g * DD + t] / cnt, 0.f);
  __syncthreads();
  float a1v = b1[t];
  for (int k = 0; k < DD; ++k) a1v = fmaf(row[k], W1[k * DD + t], a1v);
  t1[t] = fmaxf(a1v, 0.f);
  __syncthreads();
  if (t < NT) {
    float a2 = b2[t];
    for (int k = 0; k < DD; ++k) a2 = fmaf(t1[k], W2[k * NT + t], a2);
    out[g * NT + t] = a2;
  }
}

extern "C" void kernel_launch(void* const* d_in, const int* in_sizes, int n_in,
                              void* d_out, int out_size, void* d_ws,
                              size_t ws_size, hipStream_t stream) {
  const int* x = (const int*)d_in[0];
  const int* edge_index = (const int*)d_in[1];
  const int* batch = (const int*)d_in[2];
  const int* edge_attr = (const int*)d_in[3];
  const float* atom_emb = (const float*)d_in[4];
  const float* W = (const float*)d_in[5];
  const float* b = (const float*)d_in[6];
  const float* root = (const float*)d_in[7];
  const float* bond_emb = (const float*)d_in[8];
  const float* gamma = (const float*)d_in[9];
  const float* beta = (const float*)d_in[10];
  const float* W1 = (const float*)d_in[11];
  const float* b1 = (const float*)d_in[12];
  const float* W2 = (const float*)d_in[13];
  const float* b2 = (const float*)d_in[14];
  float* out = (float*)d_out;

  char* ws = (char*)d_ws;
  size_t off_b = 0;
  auto alloc = [&](size_t bytes) {
    char* p = ws + off_b;
    off_b += (bytes + 255) & ~size_t(255);
    return p;
  };
  float* h = (float*)alloc(sizeof(float) * NN * DD);
  __half* hl = (__half*)alloc(sizeof(__half) * NN * DD);
  int2* edata = (int2*)alloc(sizeof(int2) * NE);
  float* degrecip = (float*)alloc(sizeof(float) * NN);
  float* dinv = (float*)alloc(sizeof(float) * NN);
  int* degcnt = (int*)alloc(sizeof(int) * NN);
  int* incnt = (int*)alloc(sizeof(int) * NN);
  int* off = (int*)alloc(sizeof(int) * (NN + 1));
  int* cursor = (int*)alloc(sizeof(int) * NN);
  int* bsum = (int*)alloc(sizeof(int) * 128);
  float* bn_sum = (float*)alloc(sizeof(float) * DD);
  float* bn_sq = (float*)alloc(sizeof(float) * DD);
  float* bsc = (float*)alloc(sizeof(float) * DD);
  float* bsh = (float*)alloc(sizeof(float) * DD);
  int* gcount = (int*)alloc(sizeof(int) * NG);
  int* gstart = (int*)alloc(sizeof(int) * (NG + 1));
  float* hg = (float*)alloc(sizeof(float) * NG * DD);
  __half* Wf = (__half*)alloc(sizeof(__half) * NL * DD * DD);

  hipMemsetAsync(degcnt, 0, sizeof(int) * NN, stream);
  hipMemsetAsync(incnt, 0, sizeof(int) * NN, stream);
  hipMemsetAsync(cursor, 0, sizeof(int) * NN, stream);
  hipMemsetAsync(gcount, 0, sizeof(int) * NG, stream);
  hipMemsetAsync(hg, 0, sizeof(float) * NG * DD, stream);

  atom_encoder_kernel<<<(NN * 32 + 255) / 256, 256, 0, stream>>>(x, atom_emb, h);
  edge_count_kernel<<<(NE + 255) / 256, 256, 0, stream>>>(edge_index, degcnt,
                                                          incnt);
  count_kernel<<<(NN + 255) / 256, 256, 0, stream>>>(batch, gcount, NN);
  deg_fin_kernel<<<(NN + 255) / 256, 256, 0, stream>>>(degcnt, degrecip, dinv);
  wfrag_kernel<<<(NL * 8 * 4 * 64 + 255) / 256, 256, 0, stream>>>(W, Wf);

  const int nb = (NN + SCAN_B - 1) / SCAN_B;  // 98
  scan1_kernel<<<nb, 256, 0, stream>>>(incnt, off, bsum, NN);
  scan2_kernel<<<1, 128, 0, stream>>>(bsum, nb);
  scan3_kernel<<<(NN + 255) / 256, 256, 0, stream>>>(off, bsum, NN, NE);
  csr_fill_kernel<<<(NE + 255) / 256, 256, 0, stream>>>(edge_index, edge_attr,
                                                        dinv, off, cursor, edata);
  gscan_kernel<<<1, NG, 0, stream>>>(gcount, gstart);

  const int GB = (NN + 4 * CHUNK - 1) / (4 * CHUNK);  // 1924 blocks
  for (int l = 0; l < NL; ++l) {
    gemm_mfma_kernel<<<(NN + 63) / 64, 256, 0, stream>>>(
        h, Wf + l * DD * DD, b + l * DD, bsc, bsh, l > 0 ? 1 : 0, hl);
    int mode = (l < NL - 1) ? 0 : 1;
    if (mode == 0) {
      hipMemsetAsync(bn_sum, 0, sizeof(float) * DD, stream);
      hipMemsetAsync(bn_sq, 0, sizeof(float) * DD, stream);
    }
    gather_update_kernel<<<GB, 256, 0, stream>>>(
        off, edata, (const __half2*)hl, bond_emb + l * 3 * 8 * DD,
        root + l * DD, degrecip, batch, h, hg, bn_sum, bn_sq, mode);
    if (mode == 0) {
      bn_finalize_kernel<<<1, DD, 0, stream>>>(bn_sum, bn_sq, gamma + l * DD,
                                               beta + l * DD, bsc, bsh);
    }
  }

  mlp_kernel<<<NG, DD, 0, stream>>>(hg, gstart, W1, b1, W2, b2, out);
}

// Round 6
// 756.921 us; speedup vs baseline: 2.7536x; 1.0451x over previous
//
#include <hip/hip_runtime.h>
#include <hip/hip_fp16.h>

#define NN 100000
#define NE 800000
#define DD 128
#define NL 4
#define NG 512
#define NT 10
#define BN_EPS 1e-5f
#define SCAN_B 1024
#define CHUNK 8

typedef __attribute__((ext_vector_type(4))) float f32x4;
typedef __attribute__((ext_vector_type(8))) _Float16 f16x8;

__device__ __forceinline__ float atomAddF(float* p, float v) {
  return unsafeAtomicAdd(p, v);
}

// ---------------- setup kernels ----------------

__global__ __launch_bounds__(256) void atom_encoder_kernel(
    const int* __restrict__ x, const float* __restrict__ atom_emb,
    __half* __restrict__ h) {
  int idx = blockIdx.x * 256 + threadIdx.x;
  int n = idx >> 5, q = idx & 31;
  if (n >= NN) return;
  const int* xr = x + n * 9;
  float4 acc = make_float4(0.f, 0.f, 0.f, 0.f);
#pragma unroll
  for (int f = 0; f < 9; ++f) {
    const float4 v =
        *reinterpret_cast<const float4*>(&atom_emb[(f * 64 + xr[f]) * DD + q * 4]);
    acc.x += v.x; acc.y += v.y; acc.z += v.z; acc.w += v.w;
  }
  union {
    struct { __half2 a, b; } hh;
    int2 i2;
  } u;
  u.hh.a = __floats2half2_rn(acc.x, acc.y);
  u.hh.b = __floats2half2_rn(acc.z, acc.w);
  *reinterpret_cast<int2*>(&h[n * DD + q * 4]) = u.i2;
}

__global__ __launch_bounds__(256) void edge_count_kernel(
    const int* __restrict__ ei, int* __restrict__ degcnt,
    int* __restrict__ incnt) {
  int e = blockIdx.x * 256 + threadIdx.x;
  if (e < NE) {
    atomicAdd(&degcnt[ei[e]], 1);
    atomicAdd(&incnt[ei[NE + e]], 1);
  }
}

__global__ __launch_bounds__(256) void count_kernel(
    const int* __restrict__ idxs, int* __restrict__ cnt, int n) {
  int e = blockIdx.x * 256 + threadIdx.x;
  if (e < n) atomicAdd(&cnt[idxs[e]], 1);
}

__global__ __launch_bounds__(256) void deg_fin_kernel(
    const int* __restrict__ degcnt, float* __restrict__ degrecip,
    float* __restrict__ dinv) {
  int n = blockIdx.x * 256 + threadIdx.x;
  if (n < NN) {
    float dv = (float)degcnt[n] + 1.f;
    degrecip[n] = 1.f / dv;
    dinv[n] = rsqrtf(dv);
  }
}

// W -> fragment-ordered fp16: Wf[l][tile(8)][chunk(4)][lane(64)][i(8)]
__global__ __launch_bounds__(256) void wfrag_kernel(const float* __restrict__ W,
                                                    __half* __restrict__ Wf) {
  int idx = blockIdx.x * 256 + threadIdx.x;  // 4*8*4*64 = 8192
  if (idx >= NL * 8 * 4 * 64) return;
  int lane = idx & 63;
  int c = (idx >> 6) & 3;
  int t = (idx >> 8) & 7;
  int l = idx >> 11;
  const float* Wl = W + l * DD * DD;
  __half* o = Wf + idx * 8;
  int n = t * 16 + (lane & 15);
  int k0 = c * 32 + (lane >> 4) * 8;
#pragma unroll
  for (int i = 0; i < 8; ++i) o[i] = (__half)Wl[(k0 + i) * DD + n];
}

// ---------------- CSR build ----------------

__global__ __launch_bounds__(256) void scan1_kernel(
    const int* __restrict__ in, int* __restrict__ out, int* __restrict__ bsum,
    int n) {
  __shared__ int s[256];
  int base = blockIdx.x * SCAN_B + threadIdx.x * 4;
  int v[4] = {0, 0, 0, 0};
  if (base + 3 < n) {
    int4 t = *reinterpret_cast<const int4*>(&in[base]);
    v[0] = t.x; v[1] = t.y; v[2] = t.z; v[3] = t.w;
  } else {
    for (int i = 0; i < 4; ++i) v[i] = (base + i < n) ? in[base + i] : 0;
  }
  int tsum = v[0] + v[1] + v[2] + v[3];
  s[threadIdx.x] = tsum;
  __syncthreads();
  for (int d = 1; d < 256; d <<= 1) {
    int t = (threadIdx.x >= d) ? s[threadIdx.x - d] : 0;
    __syncthreads();
    s[threadIdx.x] += t;
    __syncthreads();
  }
  int run = s[threadIdx.x] - tsum;
  if (threadIdx.x == 255) bsum[blockIdx.x] = s[255];
  for (int i = 0; i < 4; ++i) {
    if (base + i < n) out[base + i] = run;
    run += v[i];
  }
}

__global__ void scan2_kernel(int* bsum, int nb) {
  __shared__ int s[128];
  int v = (threadIdx.x < nb) ? bsum[threadIdx.x] : 0;
  s[threadIdx.x] = v;
  __syncthreads();
  for (int d = 1; d < 128; d <<= 1) {
    int t = (threadIdx.x >= d) ? s[threadIdx.x - d] : 0;
    __syncthreads();
    s[threadIdx.x] += t;
    __syncthreads();
  }
  if (threadIdx.x < nb) bsum[threadIdx.x] = s[threadIdx.x] - v;
}

__global__ __launch_bounds__(256) void scan3_kernel(int* off, const int* bsum,
                                                    int n, int total) {
  int i = blockIdx.x * 256 + threadIdx.x;
  if (i < n) off[i] += bsum[i / SCAN_B];
  if (i == 0) off[n] = total;
}

// packed edge record: {src | a0<<17 | a1<<20 | a2<<23, norm_bits}
__global__ __launch_bounds__(256) void csr_fill_kernel(
    const int* __restrict__ ei, const int* __restrict__ eattr,
    const float* __restrict__ dinv, const int* __restrict__ off,
    int* __restrict__ cursor, int2* __restrict__ edata) {
  int e = blockIdx.x * 256 + threadIdx.x;
  if (e >= NE) return;
  int r = ei[e], c = ei[NE + e];
  int pos = atomicAdd(&cursor[c], 1);
  float nm = dinv[r] * dinv[c];
  int2 d;
  d.x = r | (eattr[e * 3] << 17) | (eattr[e * 3 + 1] << 20) |
        (eattr[e * 3 + 2] << 23);
  d.y = __float_as_int(nm);
  edata[off[c] + pos] = d;
}

__global__ void gscan_kernel(const int* __restrict__ gcount,
                             int* __restrict__ gstart) {
  __shared__ int s[NG];
  int v = gcount[threadIdx.x];
  s[threadIdx.x] = v;
  __syncthreads();
  for (int d = 1; d < NG; d <<= 1) {
    int t = (threadIdx.x >= d) ? s[threadIdx.x - d] : 0;
    __syncthreads();
    s[threadIdx.x] += t;
    __syncthreads();
  }
  gstart[threadIdx.x] = s[threadIdx.x] - v;
  if (threadIdx.x == NG - 1) gstart[NG] = s[NG - 1];
}

// ---------------- MFMA GEMM: hl = act(A) @ W + bias (fp16 in/out) ----------------

__global__ __launch_bounds__(256) void gemm_mfma_kernel(
    const __half* __restrict__ A, const __half* __restrict__ Wf,
    const float* __restrict__ bias, const float* __restrict__ bn_scale,
    const float* __restrict__ bn_shift, int fuse_bn, __half* __restrict__ hl) {
  const int wid = threadIdx.x >> 6, lane = threadIdx.x & 63;
  const int r0 = blockIdx.x * 64 + wid * 16;
  const int arow = min(r0 + (lane & 15), NN - 1);
  const int kb = (lane >> 4) * 8;

  f16x8 afrag[4];
#pragma unroll
  for (int c = 0; c < 4; ++c) {
    const int k0 = c * 32 + kb;
    f16x8 raw = *reinterpret_cast<const f16x8*>(&A[arow * DD + k0]);
    if (fuse_bn) {
#pragma unroll
      for (int i = 0; i < 8; ++i) {
        float v = fmaxf((float)raw[i] * bn_scale[k0 + i] + bn_shift[k0 + i], 0.f);
        raw[i] = (_Float16)v;
      }
    }
    afrag[c] = raw;
  }

  f32x4 acc[8];
#pragma unroll
  for (int t = 0; t < 8; ++t) acc[t] = (f32x4){0.f, 0.f, 0.f, 0.f};

  const f16x8* __restrict__ wf = reinterpret_cast<const f16x8*>(Wf);
#pragma unroll
  for (int t = 0; t < 8; ++t) {
#pragma unroll
    for (int c = 0; c < 4; ++c) {
      f16x8 b = wf[(t * 4 + c) * 64 + lane];
      acc[t] = __builtin_amdgcn_mfma_f32_16x16x32_f16(afrag[c], b, acc[t], 0, 0, 0);
    }
  }

  const int colb = lane & 15;
  const int rbase = r0 + (lane >> 4) * 4;
#pragma unroll
  for (int t = 0; t < 8; ++t) {
    float bb = bias[t * 16 + colb];
#pragma unroll
    for (int j = 0; j < 4; ++j) {
      int row = rbase + j;
      if (row < NN) hl[row * DD + t * 16 + colb] = (__half)(acc[t][j] + bb);
    }
  }
}

// ---------------- fused gather + update + BN stats / pool ----------------

#define PROC(PX, PY)                                                      \
  {                                                                       \
    int p_ = (PX);                                                        \
    float nm_ = __int_as_float(PY);                                       \
    int r_ = p_ & 0x1FFFF;                                                \
    int a0_ = (p_ >> 17) & 7, a1_ = (p_ >> 20) & 7, a2_ = (p_ >> 23) & 7; \
    float2 b0_ = bembS[a0_ * 64 + lane];                                  \
    float2 b1_ = bembS[(8 + a1_) * 64 + lane];                            \
    float2 b2_ = bembS[(16 + a2_) * 64 + lane];                           \
    float2 hv_ = __half22float2(hl2[r_ * 64 + lane]);                     \
    acc0 += nm_ * fmaxf(hv_.x + b0_.x + b1_.x + b2_.x, 0.f);              \
    acc1 += nm_ * fmaxf(hv_.y + b0_.y + b1_.y + b2_.y, 0.f);              \
  }

__global__ __launch_bounds__(256) void gather_update_kernel(
    const int* __restrict__ off, const int2* __restrict__ edata,
    const __half2* __restrict__ hl2, const float* __restrict__ bemb,
    const float* __restrict__ root, const float* __restrict__ degrecip,
    const int* __restrict__ batch, __half2* __restrict__ h2,
    float* __restrict__ hg, float* __restrict__ bn_sum,
    float* __restrict__ bn_sq, int mode) {  // mode 0: h+stats, 1: pool
  __shared__ float2 bembS[24 * 64];
  const float2* bemb2 = reinterpret_cast<const float2*>(bemb);
  for (int i = threadIdx.x; i < 24 * 64; i += 256) bembS[i] = bemb2[i];
  const int wid = threadIdx.x >> 6;
  const int lane = threadIdx.x & 63;
  float2 rt = *reinterpret_cast<const float2*>(&root[2 * lane]);
  float ls0 = 0, ls1 = 0, lq0 = 0, lq1 = 0;
  const int wv = blockIdx.x * 4 + wid;
  const int n0 = wv * CHUNK;
  const int n1 = min(n0 + CHUNK, NN);
  int curg = -1;
  float pg0 = 0.f, pg1 = 0.f;
  __syncthreads();
  for (int n = n0; n < n1; ++n) {
    int k0 = off[n], k1 = off[n + 1];
    float acc0 = 0.f, acc1 = 0.f;
    int k = k0;
    for (; k + 3 < k1; k += 4) {
      int4 ea = *reinterpret_cast<const int4*>(&edata[k]);
      int4 eb = *reinterpret_cast<const int4*>(&edata[k + 2]);
      PROC(ea.x, ea.y) PROC(ea.z, ea.w) PROC(eb.x, eb.y) PROC(eb.z, eb.w)
    }
    for (; k < k1; ++k) {
      int2 e0 = edata[k];
      PROC(e0.x, e0.y)
    }
    float dr = degrecip[n];
    float2 hs = __half22float2(hl2[n * 64 + lane]);
    float v0 = acc0 + fmaxf(hs.x + rt.x, 0.f) * dr;
    float v1 = acc1 + fmaxf(hs.y + rt.y, 0.f) * dr;
    if (mode == 0) {
      h2[n * 64 + lane] = __floats2half2_rn(v0, v1);
      ls0 += v0; ls1 += v1;
      lq0 += v0 * v0; lq1 += v1 * v1;
    } else {
      int g = batch[n];
      if (g != curg) {
        if (curg >= 0) {
          atomAddF(&hg[curg * DD + 2 * lane], pg0);
          atomAddF(&hg[curg * DD + 2 * lane + 1], pg1);
        }
        curg = g;
        pg0 = v0; pg1 = v1;
      } else {
        pg0 += v0; pg1 += v1;
      }
    }
  }
  if (mode == 1) {
    if (curg >= 0) {
      atomAddF(&hg[curg * DD + 2 * lane], pg0);
      atomAddF(&hg[curg * DD + 2 * lane + 1], pg1);
    }
    return;
  }
  __shared__ float s0[DD], s1[DD];
  const int d0 = 2 * lane, d1 = 2 * lane + 1;
  if (wid == 0) {
    s0[d0] = ls0; s0[d1] = ls1;
    s1[d0] = lq0; s1[d1] = lq1;
  }
  __syncthreads();
#pragma unroll
  for (int w = 1; w < 4; ++w) {
    if (wid == w) {
      s0[d0] += ls0; s0[d1] += ls1;
      s1[d0] += lq0; s1[d1] += lq1;
    }
    __syncthreads();
  }
  if (threadIdx.x < DD) {
    atomAddF(&bn_sum[threadIdx.x], s0[threadIdx.x]);
    atomAddF(&bn_sq[threadIdx.x], s1[threadIdx.x]);
  }
}

__global__ __launch_bounds__(128) void bn_finalize_kernel(
    const float* __restrict__ bn_sum, const float* __restrict__ bn_sq,
    const float* __restrict__ gamma, const float* __restrict__ beta,
    float* __restrict__ scale, float* __restrict__ shift) {
  int d = threadIdx.x;
  float mu = bn_sum[d] / (float)NN;
  float var = bn_sq[d] / (float)NN - mu * mu;
  float inv = rsqrtf(var + BN_EPS);
  float sc = gamma[d] * inv;
  scale[d] = sc;
  shift[d] = beta[d] - mu * sc;
}

// ---------------- MLP on pooled features ----------------

__global__ __launch_bounds__(128) void mlp_kernel(
    const float* __restrict__ hg, const int* __restrict__ gstart,
    const float* __restrict__ W1, const float* __restrict__ b1,
    const float* __restrict__ W2, const float* __restrict__ b2,
    float* __restrict__ out) {
  int g = blockIdx.x, t = threadIdx.x;
  float cnt = fmaxf((float)(gstart[g + 1] - gstart[g]), 1.f);
  __shared__ float row[DD], t1[DD];
  row[t] = fmaxf(hg[g * DD + t] / cnt, 0.f);
  __syncthreads();
  float a1v = b1[t];
  for (int k = 0; k < DD; ++k) a1v = fmaf(row[k], W1[k * DD + t], a1v);
  t1[t] = fmaxf(a1v, 0.f);
  __syncthreads();
  if (t < NT) {
    float a2 = b2[t];
    for (int k = 0; k < DD; ++k) a2 = fmaf(t1[k], W2[k * NT + t], a2);
    out[g * NT + t] = a2;
  }
}

extern "C" void kernel_launch(void* const* d_in, const int* in_sizes, int n_in,
                              void* d_out, int out_size, void* d_ws,
                              size_t ws_size, hipStream_t stream) {
  const int* x = (const int*)d_in[0];
  const int* edge_index = (const int*)d_in[1];
  const int* batch = (const int*)d_in[2];
  const int* edge_attr = (const int*)d_in[3];
  const float* atom_emb = (const float*)d_in[4];
  const float* W = (const float*)d_in[5];
  const float* b = (const float*)d_in[6];
  const float* root = (const float*)d_in[7];
  const float* bond_emb = (const float*)d_in[8];
  const float* gamma = (const float*)d_in[9];
  const float* beta = (const float*)d_in[10];
  const float* W1 = (const float*)d_in[11];
  const float* b1 = (const float*)d_in[12];
  const float* W2 = (const float*)d_in[13];
  const float* b2 = (const float*)d_in[14];
  float* out = (float*)d_out;

  char* ws = (char*)d_ws;
  size_t off_b = 0;
  auto alloc = [&](size_t bytes) {
    char* p = ws + off_b;
    off_b += (bytes + 255) & ~size_t(255);
    return p;
  };
  __half* h = (__half*)alloc(sizeof(__half) * NN * DD);
  __half* hl = (__half*)alloc(sizeof(__half) * NN * DD);
  int2* edata = (int2*)alloc(sizeof(int2) * NE);
  float* degrecip = (float*)alloc(sizeof(float) * NN);
  float* dinv = (float*)alloc(sizeof(float) * NN);
  int* degcnt = (int*)alloc(sizeof(int) * NN);
  int* incnt = (int*)alloc(sizeof(int) * NN);
  int* off = (int*)alloc(sizeof(int) * (NN + 1));
  int* cursor = (int*)alloc(sizeof(int) * NN);
  int* bsum = (int*)alloc(sizeof(int) * 128);
  float* bn_sum = (float*)alloc(sizeof(float) * DD);
  float* bn_sq = (float*)alloc(sizeof(float) * DD);
  float* bsc = (float*)alloc(sizeof(float) * DD);
  float* bsh = (float*)alloc(sizeof(float) * DD);
  int* gcount = (int*)alloc(sizeof(int) * NG);
  int* gstart = (int*)alloc(sizeof(int) * (NG + 1));
  float* hg = (float*)alloc(sizeof(float) * NG * DD);
  __half* Wf = (__half*)alloc(sizeof(__half) * NL * DD * DD);

  hipMemsetAsync(degcnt, 0, sizeof(int) * NN, stream);
  hipMemsetAsync(incnt, 0, sizeof(int) * NN, stream);
  hipMemsetAsync(cursor, 0, sizeof(int) * NN, stream);
  hipMemsetAsync(gcount, 0, sizeof(int) * NG, stream);
  hipMemsetAsync(hg, 0, sizeof(float) * NG * DD, stream);

  atom_encoder_kernel<<<(NN * 32 + 255) / 256, 256, 0, stream>>>(x, atom_emb, h);
  edge_count_kernel<<<(NE + 255) / 256, 256, 0, stream>>>(edge_index, degcnt,
                                                          incnt);
  count_kernel<<<(NN + 255) / 256, 256, 0, stream>>>(batch, gcount, NN);
  deg_fin_kernel<<<(NN + 255) / 256, 256, 0, stream>>>(degcnt, degrecip, dinv);
  wfrag_kernel<<<(NL * 8 * 4 * 64 + 255) / 256, 256, 0, stream>>>(W, Wf);

  const int nb = (NN + SCAN_B - 1) / SCAN_B;  // 98
  scan1_kernel<<<nb, 256, 0, stream>>>(incnt, off, bsum, NN);
  scan2_kernel<<<1, 128, 0, stream>>>(bsum, nb);
  scan3_kernel<<<(NN + 255) / 256, 256, 0, stream>>>(off, bsum, NN, NE);
  csr_fill_kernel<<<(NE + 255) / 256, 256, 0, stream>>>(edge_index, edge_attr,
                                                        dinv, off, cursor, edata);
  gscan_kernel<<<1, NG, 0, stream>>>(gcount, gstart);

  const int GB = (NN + 4 * CHUNK - 1) / (4 * CHUNK);  // 3125 blocks
  for (int l = 0; l < NL; ++l) {
    gemm_mfma_kernel<<<(NN + 63) / 64, 256, 0, stream>>>(
        h, Wf + l * DD * DD, b + l * DD, bsc, bsh, l > 0 ? 1 : 0, hl);
    int mode = (l < NL - 1) ? 0 : 1;
    if (mode == 0) {
      hipMemsetAsync(bn_sum, 0, sizeof(float) * DD, stream);
      hipMemsetAsync(bn_sq, 0, sizeof(float) * DD, stream);
    }
    gather_update_kernel<<<GB, 256, 0, stream>>>(
        off, edata, (const __half2*)hl, bond_emb + l * 3 * 8 * DD,
        root + l * DD, degrecip, batch, (__half2*)h, hg, bn_sum, bn_sq, mode);
    if (mode == 0) {
      bn_finalize_kernel<<<1, DD, 0, stream>>>(bn_sum, bn_sq, gamma + l * DD,
                                               beta + l * DD, bsc, bsh);
    }
  }

  mlp_kernel<<<NG, DD, 0, stream>>>(hg, gstart, W1, b1, W2, b2, out);
}